// Round 1
// 892.093 us; speedup vs baseline: 1.1381x; 1.1381x over previous
//
#include <hip/hip_runtime.h>
#include <stdint.h>

#define BATCH 32
#define NV 32768
#define NF 65536
#define PCOUNT (NV*3)

// Output layout (floats, concatenated in reference return order):
// input_ids      (32, 589826)      @ 0
// attention_mask (32, 589826)      @ 18874432
// codes          (32, 65536, 3, 3) @ 37748864
// dq             (32, 65536, 3, 3) @ 56623232
// sorted_faces   (32, 65536, 3)    @ 75497600
//
// Workspace: S @0 (16MB) | S2/FKa @16MB (16MB) | inv @32MB (4MB) | center | lbits
// FKb reuses S region (dead after kfacesB).

__device__ __forceinline__ unsigned fenc(float f){
  unsigned u = __float_as_uint(f);
  return (u & 0x80000000u) ? ~u : (u | 0x80000000u);
}
__device__ __forceinline__ float fdec(unsigned e){
  unsigned u = (e & 0x80000000u) ? (e & 0x7FFFFFFFu) : ~e;
  return __uint_as_float(u);
}

__global__ void kminmax(const float* __restrict__ vert, float* __restrict__ center,
                        unsigned* __restrict__ longestBits){
  int p = blockIdx.x*256 + threadIdx.x;   // 0..98303
  float mn = 3.4e38f, mx = -3.4e38f;
  #pragma unroll
  for (int b = 0; b < BATCH; ++b) {
    float v = vert[(size_t)b*PCOUNT + p];
    mn = fminf(mn, v); mx = fmaxf(mx, v);
  }
  center[p] = __fadd_rn(mn, mx) * 0.5f;
  float r = __fsub_rn(mx, mn);
  for (int off = 32; off > 0; off >>= 1) r = fmaxf(r, __shfl_down(r, off, 64));
  if ((threadIdx.x & 63) == 0) atomicMax(longestBits, __float_as_uint(r));
}

// Vertex records {fenc(z), fenc(y), fenc(x), idx} — compared lexicographically.
__global__ void kvkeys(const float* __restrict__ vert, const float* __restrict__ center,
                       const unsigned* __restrict__ longestBits, uint4* __restrict__ S){
  int id = blockIdx.x*256 + threadIdx.x;   // 0..BATCH*NV-1
  int b = id >> 15, i = id & (NV-1);
  float L = __uint_as_float(*longestBits);
  float rl = __fdiv_rn(1.0f, L);
  size_t vb = (size_t)b*PCOUNT + (size_t)i*3;
  float nx = __fsub_rn(vert[vb+0], center[i*3+0]);
  float ny = __fsub_rn(vert[vb+1], center[i*3+1]);
  float nz = __fsub_rn(vert[vb+2], center[i*3+2]);
  float x = __fmul_rn(nx, rl);
  float y = __fmul_rn(ny, rl);
  float z = __fmul_rn(nz, rl);
  uint4 s; s.x = fenc(z); s.y = fenc(y); s.z = fenc(x); s.w = (unsigned)i;
  S[id] = s;
}

__device__ __forceinline__ bool less4(uint4 a, uint4 b){
  if (a.x != b.x) return a.x < b.x;
  if (a.y != b.y) return a.y < b.y;
  if (a.z != b.z) return a.z < b.z;
  return a.w < b.w;                        // idx: unique -> total order
}
// Face record: lo=(r0<<15)|f, hi=(r2<<15)|r1 -> compare hi then lo == (r2,r1,r0,f).
__device__ __forceinline__ bool less2(uint2 a, uint2 b){
  if (a.y != b.y) return a.y < b.y;
  return a.x < b.x;                        // f: unique -> total order
}

// ---------------- LDS bitonic local sorts -----------------------------------
#define VT 2048   // vertex tile
#define FT 4096   // face tile

__global__ __launch_bounds__(256) void klocalv(uint4* __restrict__ S){
  __shared__ uint4 sh[VT];
  uint4* base = S + (size_t)blockIdx.x * VT;
  for (int i = threadIdx.x; i < VT; i += 256) sh[i] = base[i];
  __syncthreads();
  for (int k = 2; k <= VT; k <<= 1){
    for (int j = k >> 1; j > 0; j >>= 1){
      for (int t = threadIdx.x; t < VT/2; t += 256){
        int i = ((t & ~(j-1)) << 1) | (t & (j-1));
        int l = i | j;
        uint4 A = sh[i], Bv = sh[l];
        bool up = ((i & k) == 0);
        bool sw = up ? less4(Bv, A) : less4(A, Bv);
        if (sw){ sh[i] = Bv; sh[l] = A; }
      }
      __syncthreads();
    }
  }
  for (int i = threadIdx.x; i < VT; i += 256) base[i] = sh[i];
}

__global__ __launch_bounds__(256) void klocalf(uint2* __restrict__ F){
  __shared__ uint2 sh[FT];
  uint2* base = F + (size_t)blockIdx.x * FT;
  for (int i = threadIdx.x; i < FT; i += 256) sh[i] = base[i];
  __syncthreads();
  for (int k = 2; k <= FT; k <<= 1){
    for (int j = k >> 1; j > 0; j >>= 1){
      for (int t = threadIdx.x; t < FT/2; t += 256){
        int i = ((t & ~(j-1)) << 1) | (t & (j-1));
        int l = i | j;
        uint2 A = sh[i], Bv = sh[l];
        bool up = ((i & k) == 0);
        bool sw = up ? less2(Bv, A) : less2(A, Bv);
        if (sw){ sh[i] = Bv; sh[l] = A; }
      }
      __syncthreads();
    }
  }
  for (int i = threadIdx.x; i < FT; i += 256) base[i] = sh[i];
}

// ---------------- Merge-path merge rounds ------------------------------------
// Vertex: batch = 32768 recs, output chunk 2048/WG (16 chunks/batch), 8 outs/thread.
__global__ __launch_bounds__(256) void kmergev(const uint4* __restrict__ src,
                                               uint4* __restrict__ dst, int L){
  int gid = blockIdx.x;
  int b = gid >> 4, c = gid & 15;
  const uint4* base = src + ((size_t)b << 15);
  uint4* obase = dst + ((size_t)b << 15);
  int co = c * 2048;
  int pair = co / (2*L);
  int ko = co - pair*2*L;
  const uint4* A = base + (size_t)pair*2*L;
  const uint4* B = A + L;
  uint4* O = obase + (size_t)pair*2*L;
  int k0 = ko + threadIdx.x * 8;
  int lo = k0 - L; if (lo < 0) lo = 0;
  int hi = k0 < L ? k0 : L;
  while (lo < hi){
    int mid = (lo + hi) >> 1;
    if (less4(A[mid], B[k0-1-mid])) lo = mid + 1; else hi = mid;
  }
  int i = lo, j = k0 - lo;
  #pragma unroll
  for (int e = 0; e < 8; ++e){
    bool takeA = (j >= L) || (i < L && less4(A[i], B[j]));
    uint4 v = takeA ? A[i] : B[j];
    if (takeA) ++i; else ++j;
    O[k0 + e] = v;
  }
}

// Face: batch = 65536 recs, output chunk 2048/WG (32 chunks/batch), 8 outs/thread.
__global__ __launch_bounds__(256) void kmergef(const uint2* __restrict__ src,
                                               uint2* __restrict__ dst, int L){
  int gid = blockIdx.x;
  int b = gid >> 5, c = gid & 31;
  const uint2* base = src + ((size_t)b << 16);
  uint2* obase = dst + ((size_t)b << 16);
  int co = c * 2048;
  int pair = co / (2*L);
  int ko = co - pair*2*L;
  const uint2* A = base + (size_t)pair*2*L;
  const uint2* B = A + L;
  uint2* O = obase + (size_t)pair*2*L;
  int k0 = ko + threadIdx.x * 8;
  int lo = k0 - L; if (lo < 0) lo = 0;
  int hi = k0 < L ? k0 : L;
  while (lo < hi){
    int mid = (lo + hi) >> 1;
    if (less2(A[mid], B[k0-1-mid])) lo = mid + 1; else hi = mid;
  }
  int i = lo, j = k0 - lo;
  #pragma unroll
  for (int e = 0; e < 8; ++e){
    bool takeA = (j >= L) || (i < L && less2(A[i], B[j]));
    uint2 v = takeA ? A[i] : B[j];
    if (takeA) ++i; else ++j;
    O[k0 + e] = v;
  }
}
// -----------------------------------------------------------------------------

__global__ void kinv(const uint4* __restrict__ S, int* __restrict__ inv){
  int id = blockIdx.x*256 + threadIdx.x;
  int b = id >> 15, j = id & (NV-1);
  inv[(b<<15) + (int)S[id].w] = j;
}

// LDS-staged output: compute 9 quantized values per face into LDS, then emit
// all four regions with lane-contiguous (full-cacheline) stores.
// XCD-affine swizzle keeps each batch's 512KB S table on a single XCD's L2.
__global__ __launch_bounds__(256) void kfacesB(const int* __restrict__ faces,
                                               const uint4* __restrict__ S,
                                               float* __restrict__ out){
  __shared__ __align__(16) float shq[2304];   // 256 faces x 9 quantized values
  __shared__ float shm[256];                  // attention value per face
  int p = blockIdx.x;
  int l = ((p & 7) << 10) | (p >> 3);         // 8192 = 8 x 1024, bijective
  int b = l >> 8, c = l & 255;
  int t = threadIdx.x;
  {
    #pragma clang fp contract(off)
    size_t fb = ((size_t)(l*256 + t))*3;
    int f0 = faces[fb+0], f1 = faces[fb+1], f2 = faces[fb+2];
    bool mask = (f0 != -1) & (f1 != -1) & (f2 != -1);
    shm[t] = mask ? 1.0f : 0.0f;
    int fv[3] = {mask ? f0 : 0, mask ? f1 : 0, mask ? f2 : 0};
    #pragma unroll
    for (int k = 0; k < 3; ++k){
      uint4 s = S[(b<<15) + fv[k]];
      float cco[3]; cco[0] = fdec(s.z); cco[1] = fdec(s.y); cco[2] = fdec(s.x); // (x,y,z)
      #pragma unroll
      for (int cc = 0; cc < 3; ++cc){
        float tt = ((cco[cc] + 1.0f) * 0.5f) * 128.0f - 0.5f;
        float rq = rintf(tt);
        int qi = (int)rq;
        qi = qi < 0 ? 0 : (qi > 127 ? 127 : qi);
        shq[t*9 + k*3 + cc] = (float)qi;
      }
    }
  }
  __syncthreads();
  // codes/dq: 16B-aligned block bases -> float4 stores (576 per block)
  float4* cp = (float4*)(out + 37748864 + (size_t)l*2304);
  float4* dp = (float4*)(out + 56623232 + (size_t)l*2304);
  for (int r = t; r < 576; r += 256){
    int e0 = r*4;
    float4 q = *(const float4*)&shq[e0];
    float m0 = shm[(unsigned)(e0  )/9u];
    float m1 = shm[(unsigned)(e0+1)/9u];
    float m2 = shm[(unsigned)(e0+2)/9u];
    float m3 = shm[(unsigned)(e0+3)/9u];
    float4 cv;
    cv.x = m0 != 0.0f ? q.x : -1.0f;
    cv.y = m1 != 0.0f ? q.y : -1.0f;
    cv.z = m2 != 0.0f ? q.z : -1.0f;
    cv.w = m3 != 0.0f ? q.w : -1.0f;
    cp[r] = cv;
    dp[r] = q;
  }
  // ids/attn: +1 float offset (misaligned) -> dense scalar dword stores
  size_t idsBase  = (size_t)b*589826 + 1 + (size_t)c*2304;
  size_t attnBase = 18874432 + idsBase;
  #pragma unroll
  for (int r = 0; r < 9; ++r){
    int idx = r*256 + t;
    float q = shq[idx];
    float m = shm[(unsigned)idx/9u];
    float cv = m != 0.0f ? q : -1.0f;
    out[idsBase + idx]  = cv;
    out[attnBase + idx] = m;
  }
  if (c == 0 && t == 0){
    out[(size_t)b*589826]                     = -1.0f;
    out[(size_t)b*589826 + 589825]            = -1.0f;
    out[18874432 + (size_t)b*589826]          = -1.0f;
    out[18874432 + (size_t)b*589826 + 589825] = -1.0f;
  }
}

__global__ void kfacesFK(const int* __restrict__ faces, const int* __restrict__ inv,
                         uint2* __restrict__ FK){
  int id = blockIdx.x*256 + threadIdx.x;
  int b = id >> 16, f = id & (NF-1);
  size_t fb = (size_t)id*3;
  int f0 = faces[fb+0], f1 = faces[fb+1], f2 = faces[fb+2];
  unsigned r0 = (unsigned)inv[(b<<15) + (f0 & (NV-1))];
  unsigned r1 = (unsigned)inv[(b<<15) + (f1 & (NV-1))];
  unsigned r2 = (unsigned)inv[(b<<15) + (f2 & (NV-1))];
  uint2 r; r.x = (r0 << 15) | (unsigned)f; r.y = (r2 << 15) | r1;
  FK[id] = r;
}

// LDS-staged transpose: uint2 coalesced in, 3 dense dword streams out.
__global__ __launch_bounds__(256) void ksfout(const uint2* __restrict__ FK,
                                              float* __restrict__ out){
  __shared__ float sh[768];
  int id = blockIdx.x*256 + threadIdx.x;
  uint2 r = FK[id];
  int t = threadIdx.x;
  sh[t*3+0] = (float)(r.x >> 15);          // r0
  sh[t*3+1] = (float)(r.y & 0x7FFFu);      // r1
  sh[t*3+2] = (float)(r.y >> 15);          // r2
  __syncthreads();
  size_t base = 75497600 + (size_t)blockIdx.x*768;
  out[base +       t] = sh[t];
  out[base + 256 + t] = sh[256 + t];
  out[base + 512 + t] = sh[512 + t];
}

extern "C" void kernel_launch(void* const* d_in, const int* in_sizes, int n_in,
                              void* d_out, int out_size, void* d_ws, size_t ws_size,
                              hipStream_t stream){
  const float* vert  = (const float*)d_in[0];
  const int*   faces = (const int*)d_in[1];
  float* out = (float*)d_out;

  uint4*    S           = (uint4*)d_ws;                         // 16 MiB
  uint4*    S2          = (uint4*)((char*)d_ws + 16777216);     // 16 MiB
  uint2*    FKa         = (uint2*)((char*)d_ws + 16777216);     // reuses S2
  uint2*    FKb         = (uint2*)d_ws;                         // reuses S
  int*      inv         = (int*)((char*)d_ws + 33554432);       // 4 MiB
  float*    center      = (float*)((char*)d_ws + 37748736);     // 384 KiB
  unsigned* longestBits = (unsigned*)((char*)d_ws + 38141952);  // 4 B

  hipMemsetAsync(longestBits, 0, 4, stream);
  kminmax<<<PCOUNT/256, 256, 0, stream>>>(vert, center, longestBits);
  kvkeys<<<(BATCH*NV)/256, 256, 0, stream>>>(vert, center, longestBits, S);

  // vertex sort: local 2048-tiles, then 4 merge rounds (ends in S)
  klocalv<<<BATCH*(NV/VT), 256, 0, stream>>>(S);
  kmergev<<<BATCH*16, 256, 0, stream>>>(S,  S2, 2048);
  kmergev<<<BATCH*16, 256, 0, stream>>>(S2, S,  4096);
  kmergev<<<BATCH*16, 256, 0, stream>>>(S,  S2, 8192);
  kmergev<<<BATCH*16, 256, 0, stream>>>(S2, S,  16384);

  kinv<<<(BATCH*NV)/256, 256, 0, stream>>>(S, inv);
  kfacesB<<<(BATCH*NF)/256, 256, 0, stream>>>(faces, S, out);   // S dead after
  kfacesFK<<<(BATCH*NF)/256, 256, 0, stream>>>(faces, inv, FKa);

  // face sort: local 4096-tiles, then 4 merge rounds (ends in FKa)
  klocalf<<<BATCH*(NF/FT), 256, 0, stream>>>(FKa);
  kmergef<<<BATCH*32, 256, 0, stream>>>(FKa, FKb, 4096);
  kmergef<<<BATCH*32, 256, 0, stream>>>(FKb, FKa, 8192);
  kmergef<<<BATCH*32, 256, 0, stream>>>(FKa, FKb, 16384);
  kmergef<<<BATCH*32, 256, 0, stream>>>(FKb, FKa, 32768);

  ksfout<<<(BATCH*NF)/256, 256, 0, stream>>>(FKa, out);
}

// Round 2
// 781.314 us; speedup vs baseline: 1.2995x; 1.1418x over previous
//
#include <hip/hip_runtime.h>
#include <stdint.h>

#define BATCH 32
#define NV 32768
#define NF 65536
#define PCOUNT (NV*3)

// Output layout (floats, concatenated in reference return order):
// input_ids      (32, 589826)      @ 0
// attention_mask (32, 589826)      @ 18874432
// codes          (32, 65536, 3, 3) @ 37748864
// dq             (32, 65536, 3, 3) @ 56623232
// sorted_faces   (32, 65536, 3)    @ 75497600
//
// Workspace: S @0 (16MB) | S2/FKa @16MB (16MB) | inv @32MB (4MB) | center | lbits
// FKb reuses S region (dead after kfacesB).

__device__ __forceinline__ unsigned fenc(float f){
  unsigned u = __float_as_uint(f);
  return (u & 0x80000000u) ? ~u : (u | 0x80000000u);
}
__device__ __forceinline__ float fdec(unsigned e){
  unsigned u = (e & 0x80000000u) ? (e & 0x7FFFFFFFu) : ~e;
  return __uint_as_float(u);
}

__global__ void kminmax(const float* __restrict__ vert, float* __restrict__ center,
                        unsigned* __restrict__ longestBits){
  int p = blockIdx.x*256 + threadIdx.x;   // 0..98303
  float mn = 3.4e38f, mx = -3.4e38f;
  #pragma unroll
  for (int b = 0; b < BATCH; ++b) {
    float v = vert[(size_t)b*PCOUNT + p];
    mn = fminf(mn, v); mx = fmaxf(mx, v);
  }
  center[p] = __fadd_rn(mn, mx) * 0.5f;
  float r = __fsub_rn(mx, mn);
  for (int off = 32; off > 0; off >>= 1) r = fmaxf(r, __shfl_down(r, off, 64));
  if ((threadIdx.x & 63) == 0) atomicMax(longestBits, __float_as_uint(r));
}

__device__ __forceinline__ bool less4(uint4 a, uint4 b){
  if (a.x != b.x) return a.x < b.x;
  if (a.y != b.y) return a.y < b.y;
  if (a.z != b.z) return a.z < b.z;
  return a.w < b.w;                        // idx: unique -> total order
}
// Face record: lo=(r0<<15)|f, hi=(r2<<15)|r1 -> compare hi then lo == (r2,r1,r0,f).
__device__ __forceinline__ bool less2(uint2 a, uint2 b){
  if (a.y != b.y) return a.y < b.y;
  return a.x < b.x;                        // f: unique -> total order
}

// ---------------- LDS bitonic local sorts (fused key generation) -------------
#define VT 2048   // vertex tile
#define FT 4096   // face tile

// Fused kvkeys+local sort: build {fenc(z),fenc(y),fenc(x),idx} in LDS, sort, write S.
__global__ __launch_bounds__(256) void klocalv(const float* __restrict__ vert,
                                               const float* __restrict__ center,
                                               const unsigned* __restrict__ longestBits,
                                               uint4* __restrict__ S){
  __shared__ uint4 sh[VT];
  int blockBase = blockIdx.x * VT;        // tiles never cross batch boundary
  float L = __uint_as_float(*longestBits);
  float rl = __fdiv_rn(1.0f, L);
  for (int i = threadIdx.x; i < VT; i += 256){
    int id = blockBase + i;
    int vi = id & (NV-1);
    size_t vb = (size_t)(id >> 15)*PCOUNT + (size_t)vi*3;
    float nx = __fsub_rn(vert[vb+0], center[vi*3+0]);
    float ny = __fsub_rn(vert[vb+1], center[vi*3+1]);
    float nz = __fsub_rn(vert[vb+2], center[vi*3+2]);
    float x = __fmul_rn(nx, rl);
    float y = __fmul_rn(ny, rl);
    float z = __fmul_rn(nz, rl);
    uint4 s; s.x = fenc(z); s.y = fenc(y); s.z = fenc(x); s.w = (unsigned)vi;
    sh[i] = s;
  }
  __syncthreads();
  for (int k = 2; k <= VT; k <<= 1){
    for (int j = k >> 1; j > 0; j >>= 1){
      for (int t = threadIdx.x; t < VT/2; t += 256){
        int i = ((t & ~(j-1)) << 1) | (t & (j-1));
        int l = i | j;
        uint4 A = sh[i], Bv = sh[l];
        bool up = ((i & k) == 0);
        bool sw = up ? less4(Bv, A) : less4(A, Bv);
        if (sw){ sh[i] = Bv; sh[l] = A; }
      }
      __syncthreads();
    }
  }
  uint4* base = S + (size_t)blockBase;
  for (int i = threadIdx.x; i < VT; i += 256) base[i] = sh[i];
}

// Fused kfacesFK+local sort: build face records in LDS, sort, write F.
__global__ __launch_bounds__(256) void klocalf(const int* __restrict__ faces,
                                               const int* __restrict__ inv,
                                               uint2* __restrict__ F){
  __shared__ uint2 sh[FT];
  int blockBase = blockIdx.x * FT;        // tiles never cross batch boundary
  int b = blockBase >> 16;
  const int* invb = inv + (b << 15);
  for (int i = threadIdx.x; i < FT; i += 256){
    int id = blockBase + i;
    int f = id & (NF-1);
    size_t fb = (size_t)id*3;
    int f0 = faces[fb+0], f1 = faces[fb+1], f2 = faces[fb+2];
    unsigned r0 = (unsigned)invb[f0 & (NV-1)];
    unsigned r1 = (unsigned)invb[f1 & (NV-1)];
    unsigned r2 = (unsigned)invb[f2 & (NV-1)];
    uint2 r; r.x = (r0 << 15) | (unsigned)f; r.y = (r2 << 15) | r1;
    sh[i] = r;
  }
  __syncthreads();
  for (int k = 2; k <= FT; k <<= 1){
    for (int j = k >> 1; j > 0; j >>= 1){
      for (int t = threadIdx.x; t < FT/2; t += 256){
        int i = ((t & ~(j-1)) << 1) | (t & (j-1));
        int l = i | j;
        uint2 A = sh[i], Bv = sh[l];
        bool up = ((i & k) == 0);
        bool sw = up ? less2(Bv, A) : less2(A, Bv);
        if (sw){ sh[i] = Bv; sh[l] = A; }
      }
      __syncthreads();
    }
  }
  uint2* base = F + (size_t)blockBase;
  for (int i = threadIdx.x; i < FT; i += 256) base[i] = sh[i];
}

// ---------------- LDS-staged merge-path merge rounds --------------------------
// Block-level: 2 threads find the block's diagonal splits; the block's exact
// 2048-record input window is loaded coalesced into LDS; per-thread search and
// 8-way merge then run against LDS instead of global.

__global__ __launch_bounds__(256) void kmergev(const uint4* __restrict__ src,
                                               uint4* __restrict__ dst, int L){
  __shared__ uint4 sh[2048];
  __shared__ int sAB[2];
  int gid = blockIdx.x;
  int b = gid >> 4, c = gid & 15;
  const uint4* base = src + ((size_t)b << 15);
  uint4* obase = dst + ((size_t)b << 15);
  int co = c * 2048;
  int pair = co / (2*L);
  int ko = co - pair*2*L;
  const uint4* A = base + (size_t)pair*2*L;
  const uint4* B = A + L;
  uint4* O = obase + (size_t)pair*2*L + ko;
  if (threadIdx.x < 2){
    int k = ko + (int)threadIdx.x * 2048;
    int lo = k - L; if (lo < 0) lo = 0;
    int hi = k < L ? k : L;
    while (lo < hi){
      int mid = (lo + hi) >> 1;
      if (less4(A[mid], B[k-1-mid])) lo = mid + 1; else hi = mid;
    }
    sAB[threadIdx.x] = lo;
  }
  __syncthreads();
  int aStart = sAB[0];
  int na = sAB[1] - aStart;
  int nb = 2048 - na;
  int bStart = ko - aStart;
  for (int i = threadIdx.x; i < 2048; i += 256)
    sh[i] = (i < na) ? A[aStart + i] : B[bStart + (i - na)];
  __syncthreads();
  int k0 = threadIdx.x * 8;
  int lo = k0 - nb; if (lo < 0) lo = 0;
  int hi = k0 < na ? k0 : na;
  while (lo < hi){
    int mid = (lo + hi) >> 1;
    if (less4(sh[mid], sh[na + k0-1-mid])) lo = mid + 1; else hi = mid;
  }
  int i = lo, j = k0 - lo;
  #pragma unroll
  for (int e = 0; e < 8; ++e){
    bool takeA = (j >= nb) || (i < na && less4(sh[i], sh[na + j]));
    uint4 v = takeA ? sh[i] : sh[na + j];
    if (takeA) ++i; else ++j;
    O[k0 + e] = v;
  }
}

__global__ __launch_bounds__(256) void kmergef(const uint2* __restrict__ src,
                                               uint2* __restrict__ dst, int L){
  __shared__ uint2 sh[2048];
  __shared__ int sAB[2];
  int gid = blockIdx.x;
  int b = gid >> 5, c = gid & 31;
  const uint2* base = src + ((size_t)b << 16);
  uint2* obase = dst + ((size_t)b << 16);
  int co = c * 2048;
  int pair = co / (2*L);
  int ko = co - pair*2*L;
  const uint2* A = base + (size_t)pair*2*L;
  const uint2* B = A + L;
  uint2* O = obase + (size_t)pair*2*L + ko;
  if (threadIdx.x < 2){
    int k = ko + (int)threadIdx.x * 2048;
    int lo = k - L; if (lo < 0) lo = 0;
    int hi = k < L ? k : L;
    while (lo < hi){
      int mid = (lo + hi) >> 1;
      if (less2(A[mid], B[k-1-mid])) lo = mid + 1; else hi = mid;
    }
    sAB[threadIdx.x] = lo;
  }
  __syncthreads();
  int aStart = sAB[0];
  int na = sAB[1] - aStart;
  int nb = 2048 - na;
  int bStart = ko - aStart;
  for (int i = threadIdx.x; i < 2048; i += 256)
    sh[i] = (i < na) ? A[aStart + i] : B[bStart + (i - na)];
  __syncthreads();
  int k0 = threadIdx.x * 8;
  int lo = k0 - nb; if (lo < 0) lo = 0;
  int hi = k0 < na ? k0 : na;
  while (lo < hi){
    int mid = (lo + hi) >> 1;
    if (less2(sh[mid], sh[na + k0-1-mid])) lo = mid + 1; else hi = mid;
  }
  int i = lo, j = k0 - lo;
  #pragma unroll
  for (int e = 0; e < 8; ++e){
    bool takeA = (j >= nb) || (i < na && less2(sh[i], sh[na + j]));
    uint2 v = takeA ? sh[i] : sh[na + j];
    if (takeA) ++i; else ++j;
    O[k0 + e] = v;
  }
}

// Final face merge (L=32768): merge in LDS, decode ranks, write sorted_faces
// floats directly (3 dense streams) — replaces the old last round + ksfout.
__global__ __launch_bounds__(256) void kmergefOut(const uint2* __restrict__ src,
                                                  float* __restrict__ out){
  __shared__ __align__(16) float shf[6144];   // 24 KB; aliased as uint2[2048] below
  __shared__ int sAB[2];
  uint2* sh = (uint2*)shf;
  const int L = 32768;
  int gid = blockIdx.x;                       // 1024 = 32 batches x 32 chunks
  int b = gid >> 5, c = gid & 31;
  const uint2* A = src + ((size_t)b << 16);
  const uint2* B = A + L;
  int ko = c * 2048;
  if (threadIdx.x < 2){
    int k = ko + (int)threadIdx.x * 2048;
    int lo = k - L; if (lo < 0) lo = 0;
    int hi = k < L ? k : L;
    while (lo < hi){
      int mid = (lo + hi) >> 1;
      if (less2(A[mid], B[k-1-mid])) lo = mid + 1; else hi = mid;
    }
    sAB[threadIdx.x] = lo;
  }
  __syncthreads();
  int aStart = sAB[0];
  int na = sAB[1] - aStart;
  int nb = 2048 - na;
  int bStart = ko - aStart;
  for (int i = threadIdx.x; i < 2048; i += 256)
    sh[i] = (i < na) ? A[aStart + i] : B[bStart + (i - na)];
  __syncthreads();
  int k0 = threadIdx.x * 8;
  int lo = k0 - nb; if (lo < 0) lo = 0;
  int hi = k0 < na ? k0 : na;
  while (lo < hi){
    int mid = (lo + hi) >> 1;
    if (less2(sh[mid], sh[na + k0-1-mid])) lo = mid + 1; else hi = mid;
  }
  int i = lo, j = k0 - lo;
  uint2 v[8];
  #pragma unroll
  for (int e = 0; e < 8; ++e){
    bool takeA = (j >= nb) || (i < na && less2(sh[i], sh[na + j]));
    v[e] = takeA ? sh[i] : sh[na + j];
    if (takeA) ++i; else ++j;
  }
  __syncthreads();                            // all LDS src reads done
  #pragma unroll
  for (int e = 0; e < 8; ++e){
    int o = (k0 + e) * 3;
    shf[o+0] = (float)(v[e].x >> 15);         // r0
    shf[o+1] = (float)(v[e].y & 0x7FFFu);     // r1
    shf[o+2] = (float)(v[e].y >> 15);         // r2
  }
  __syncthreads();
  size_t basef = 75497600 + ((size_t)b*65536 + (size_t)ko)*3;
  for (int q = threadIdx.x; q < 6144; q += 256) out[basef + q] = shf[q];
}
// -----------------------------------------------------------------------------

__global__ void kinv(const uint4* __restrict__ S, int* __restrict__ inv){
  int id = blockIdx.x*256 + threadIdx.x;
  int b = id >> 15, j = id & (NV-1);
  inv[(b<<15) + (int)S[id].w] = j;
}

// LDS-staged output: compute 9 quantized values per face into LDS, then emit
// all four regions with lane-contiguous (full-cacheline) stores.
// XCD-affine swizzle keeps each batch's 512KB S table on a single XCD's L2.
__global__ __launch_bounds__(256) void kfacesB(const int* __restrict__ faces,
                                               const uint4* __restrict__ S,
                                               float* __restrict__ out){
  __shared__ __align__(16) float shq[2304];   // 256 faces x 9 quantized values
  __shared__ float shm[256];                  // attention value per face
  int p = blockIdx.x;
  int l = ((p & 7) << 10) | (p >> 3);         // 8192 = 8 x 1024, bijective
  int b = l >> 8, c = l & 255;
  int t = threadIdx.x;
  {
    #pragma clang fp contract(off)
    size_t fb = ((size_t)(l*256 + t))*3;
    int f0 = faces[fb+0], f1 = faces[fb+1], f2 = faces[fb+2];
    bool mask = (f0 != -1) & (f1 != -1) & (f2 != -1);
    shm[t] = mask ? 1.0f : 0.0f;
    int fv[3] = {mask ? f0 : 0, mask ? f1 : 0, mask ? f2 : 0};
    #pragma unroll
    for (int k = 0; k < 3; ++k){
      uint4 s = S[(b<<15) + fv[k]];
      float cco[3]; cco[0] = fdec(s.z); cco[1] = fdec(s.y); cco[2] = fdec(s.x); // (x,y,z)
      #pragma unroll
      for (int cc = 0; cc < 3; ++cc){
        float tt = ((cco[cc] + 1.0f) * 0.5f) * 128.0f - 0.5f;
        float rq = rintf(tt);
        int qi = (int)rq;
        qi = qi < 0 ? 0 : (qi > 127 ? 127 : qi);
        shq[t*9 + k*3 + cc] = (float)qi;
      }
    }
  }
  __syncthreads();
  // codes/dq: 16B-aligned block bases -> float4 stores (576 per block)
  float4* cp = (float4*)(out + 37748864 + (size_t)l*2304);
  float4* dp = (float4*)(out + 56623232 + (size_t)l*2304);
  for (int r = t; r < 576; r += 256){
    int e0 = r*4;
    float4 q = *(const float4*)&shq[e0];
    float m0 = shm[(unsigned)(e0  )/9u];
    float m1 = shm[(unsigned)(e0+1)/9u];
    float m2 = shm[(unsigned)(e0+2)/9u];
    float m3 = shm[(unsigned)(e0+3)/9u];
    float4 cv;
    cv.x = m0 != 0.0f ? q.x : -1.0f;
    cv.y = m1 != 0.0f ? q.y : -1.0f;
    cv.z = m2 != 0.0f ? q.z : -1.0f;
    cv.w = m3 != 0.0f ? q.w : -1.0f;
    cp[r] = cv;
    dp[r] = q;
  }
  // ids/attn: +1 float offset (misaligned) -> dense scalar dword stores
  size_t idsBase  = (size_t)b*589826 + 1 + (size_t)c*2304;
  size_t attnBase = 18874432 + idsBase;
  #pragma unroll
  for (int r = 0; r < 9; ++r){
    int idx = r*256 + t;
    float q = shq[idx];
    float m = shm[(unsigned)idx/9u];
    float cv = m != 0.0f ? q : -1.0f;
    out[idsBase + idx]  = cv;
    out[attnBase + idx] = m;
  }
  if (c == 0 && t == 0){
    out[(size_t)b*589826]                     = -1.0f;
    out[(size_t)b*589826 + 589825]            = -1.0f;
    out[18874432 + (size_t)b*589826]          = -1.0f;
    out[18874432 + (size_t)b*589826 + 589825] = -1.0f;
  }
}

extern "C" void kernel_launch(void* const* d_in, const int* in_sizes, int n_in,
                              void* d_out, int out_size, void* d_ws, size_t ws_size,
                              hipStream_t stream){
  const float* vert  = (const float*)d_in[0];
  const int*   faces = (const int*)d_in[1];
  float* out = (float*)d_out;

  uint4*    S           = (uint4*)d_ws;                         // 16 MiB
  uint4*    S2          = (uint4*)((char*)d_ws + 16777216);     // 16 MiB
  uint2*    FKa         = (uint2*)((char*)d_ws + 16777216);     // reuses S2
  uint2*    FKb         = (uint2*)d_ws;                         // reuses S
  int*      inv         = (int*)((char*)d_ws + 33554432);       // 4 MiB
  float*    center      = (float*)((char*)d_ws + 37748736);     // 384 KiB
  unsigned* longestBits = (unsigned*)((char*)d_ws + 38141952);  // 4 B

  hipMemsetAsync(longestBits, 0, 4, stream);
  kminmax<<<PCOUNT/256, 256, 0, stream>>>(vert, center, longestBits);

  // vertex sort: fused keygen + local 2048-tiles, then 4 merge rounds (ends in S)
  klocalv<<<BATCH*(NV/VT), 256, 0, stream>>>(vert, center, longestBits, S);
  kmergev<<<BATCH*16, 256, 0, stream>>>(S,  S2, 2048);
  kmergev<<<BATCH*16, 256, 0, stream>>>(S2, S,  4096);
  kmergev<<<BATCH*16, 256, 0, stream>>>(S,  S2, 8192);
  kmergev<<<BATCH*16, 256, 0, stream>>>(S2, S,  16384);

  kinv<<<(BATCH*NV)/256, 256, 0, stream>>>(S, inv);
  kfacesB<<<(BATCH*NF)/256, 256, 0, stream>>>(faces, S, out);   // S dead after

  // face sort: fused FK keygen + local 4096-tiles, 3 merge rounds, final+output
  klocalf<<<BATCH*(NF/FT), 256, 0, stream>>>(faces, inv, FKa);
  kmergef<<<BATCH*32, 256, 0, stream>>>(FKa, FKb, 4096);
  kmergef<<<BATCH*32, 256, 0, stream>>>(FKb, FKa, 8192);
  kmergef<<<BATCH*32, 256, 0, stream>>>(FKa, FKb, 16384);
  kmergefOut<<<BATCH*32, 256, 0, stream>>>(FKb, out);
}

// Round 3
// 774.983 us; speedup vs baseline: 1.3101x; 1.0082x over previous
//
#include <hip/hip_runtime.h>
#include <stdint.h>

#define BATCH 32
#define NV 32768
#define NF 65536
#define PCOUNT (NV*3)

// Output layout (floats, concatenated in reference return order):
// input_ids      (32, 589826)      @ 0
// attention_mask (32, 589826)      @ 18874432
// codes          (32, 65536, 3, 3) @ 37748864
// dq             (32, 65536, 3, 3) @ 56623232
// sorted_faces   (32, 65536, 3)    @ 75497600
//
// Workspace: S @0 (16MB) | S2/FKa/Q @16MB (16MB) | inv @32MB (4MB) | center | lbits
// FKb reuses S region (dead after kinvq).
// Q (4MB) aliases the FKa region: written by kinvq, read by kfacesB, then
// overwritten by klocalf — all stream-ordered, no overlap of live ranges.

__device__ __forceinline__ unsigned fenc(float f){
  unsigned u = __float_as_uint(f);
  return (u & 0x80000000u) ? ~u : (u | 0x80000000u);
}
__device__ __forceinline__ float fdec(unsigned e){
  unsigned u = (e & 0x80000000u) ? (e & 0x7FFFFFFFu) : ~e;
  return __uint_as_float(u);
}

__global__ void kminmax(const float* __restrict__ vert, float* __restrict__ center,
                        unsigned* __restrict__ longestBits){
  int p = blockIdx.x*256 + threadIdx.x;   // 0..98303
  float mn = 3.4e38f, mx = -3.4e38f;
  #pragma unroll
  for (int b = 0; b < BATCH; ++b) {
    float v = vert[(size_t)b*PCOUNT + p];
    mn = fminf(mn, v); mx = fmaxf(mx, v);
  }
  center[p] = __fadd_rn(mn, mx) * 0.5f;
  float r = __fsub_rn(mx, mn);
  for (int off = 32; off > 0; off >>= 1) r = fmaxf(r, __shfl_down(r, off, 64));
  if ((threadIdx.x & 63) == 0) atomicMax(longestBits, __float_as_uint(r));
}

__device__ __forceinline__ bool less4(uint4 a, uint4 b){
  if (a.x != b.x) return a.x < b.x;
  if (a.y != b.y) return a.y < b.y;
  if (a.z != b.z) return a.z < b.z;
  return a.w < b.w;                        // idx: unique -> total order
}
// Face record: lo=(r0<<15)|f, hi=(r2<<15)|r1 -> compare hi then lo == (r2,r1,r0,f).
__device__ __forceinline__ bool less2(uint2 a, uint2 b){
  if (a.y != b.y) return a.y < b.y;
  return a.x < b.x;                        // f: unique -> total order
}

// ---------------- LDS bitonic local sorts (fused key generation) -------------
#define VT 2048   // vertex tile
#define FT 4096   // face tile

// Fused kvkeys+local sort: build {fenc(z),fenc(y),fenc(x),idx} in LDS, sort, write S.
__global__ __launch_bounds__(256) void klocalv(const float* __restrict__ vert,
                                               const float* __restrict__ center,
                                               const unsigned* __restrict__ longestBits,
                                               uint4* __restrict__ S){
  __shared__ uint4 sh[VT];
  int blockBase = blockIdx.x * VT;        // tiles never cross batch boundary
  float L = __uint_as_float(*longestBits);
  float rl = __fdiv_rn(1.0f, L);
  for (int i = threadIdx.x; i < VT; i += 256){
    int id = blockBase + i;
    int vi = id & (NV-1);
    size_t vb = (size_t)(id >> 15)*PCOUNT + (size_t)vi*3;
    float nx = __fsub_rn(vert[vb+0], center[vi*3+0]);
    float ny = __fsub_rn(vert[vb+1], center[vi*3+1]);
    float nz = __fsub_rn(vert[vb+2], center[vi*3+2]);
    float x = __fmul_rn(nx, rl);
    float y = __fmul_rn(ny, rl);
    float z = __fmul_rn(nz, rl);
    uint4 s; s.x = fenc(z); s.y = fenc(y); s.z = fenc(x); s.w = (unsigned)vi;
    sh[i] = s;
  }
  __syncthreads();
  for (int k = 2; k <= VT; k <<= 1){
    for (int j = k >> 1; j > 0; j >>= 1){
      for (int t = threadIdx.x; t < VT/2; t += 256){
        int i = ((t & ~(j-1)) << 1) | (t & (j-1));
        int l = i | j;
        uint4 A = sh[i], Bv = sh[l];
        bool up = ((i & k) == 0);
        bool sw = up ? less4(Bv, A) : less4(A, Bv);
        if (sw){ sh[i] = Bv; sh[l] = A; }
      }
      __syncthreads();
    }
  }
  uint4* base = S + (size_t)blockBase;
  for (int i = threadIdx.x; i < VT; i += 256) base[i] = sh[i];
}

// Fused kfacesFK+local sort: build face records in LDS, sort, write F.
__global__ __launch_bounds__(256) void klocalf(const int* __restrict__ faces,
                                               const int* __restrict__ inv,
                                               uint2* __restrict__ F){
  __shared__ uint2 sh[FT];
  int blockBase = blockIdx.x * FT;        // tiles never cross batch boundary
  int b = blockBase >> 16;
  const int* invb = inv + (b << 15);
  for (int i = threadIdx.x; i < FT; i += 256){
    int id = blockBase + i;
    int f = id & (NF-1);
    size_t fb = (size_t)id*3;
    int f0 = faces[fb+0], f1 = faces[fb+1], f2 = faces[fb+2];
    unsigned r0 = (unsigned)invb[f0 & (NV-1)];
    unsigned r1 = (unsigned)invb[f1 & (NV-1)];
    unsigned r2 = (unsigned)invb[f2 & (NV-1)];
    uint2 r; r.x = (r0 << 15) | (unsigned)f; r.y = (r2 << 15) | r1;
    sh[i] = r;
  }
  __syncthreads();
  for (int k = 2; k <= FT; k <<= 1){
    for (int j = k >> 1; j > 0; j >>= 1){
      for (int t = threadIdx.x; t < FT/2; t += 256){
        int i = ((t & ~(j-1)) << 1) | (t & (j-1));
        int l = i | j;
        uint2 A = sh[i], Bv = sh[l];
        bool up = ((i & k) == 0);
        bool sw = up ? less2(Bv, A) : less2(A, Bv);
        if (sw){ sh[i] = Bv; sh[l] = A; }
      }
      __syncthreads();
    }
  }
  uint2* base = F + (size_t)blockBase;
  for (int i = threadIdx.x; i < FT; i += 256) base[i] = sh[i];
}

// ---------------- LDS-staged merge-path merge rounds --------------------------
// Block-level: 2 threads find the block's diagonal splits; the block's exact
// 2048-record input window is loaded coalesced into LDS; per-thread search and
// 8-way merge then run against LDS instead of global.

__global__ __launch_bounds__(256) void kmergev(const uint4* __restrict__ src,
                                               uint4* __restrict__ dst, int L){
  __shared__ uint4 sh[2048];
  __shared__ int sAB[2];
  int gid = blockIdx.x;
  int b = gid >> 4, c = gid & 15;
  const uint4* base = src + ((size_t)b << 15);
  uint4* obase = dst + ((size_t)b << 15);
  int co = c * 2048;
  int pair = co / (2*L);
  int ko = co - pair*2*L;
  const uint4* A = base + (size_t)pair*2*L;
  const uint4* B = A + L;
  uint4* O = obase + (size_t)pair*2*L + ko;
  if (threadIdx.x < 2){
    int k = ko + (int)threadIdx.x * 2048;
    int lo = k - L; if (lo < 0) lo = 0;
    int hi = k < L ? k : L;
    while (lo < hi){
      int mid = (lo + hi) >> 1;
      if (less4(A[mid], B[k-1-mid])) lo = mid + 1; else hi = mid;
    }
    sAB[threadIdx.x] = lo;
  }
  __syncthreads();
  int aStart = sAB[0];
  int na = sAB[1] - aStart;
  int nb = 2048 - na;
  int bStart = ko - aStart;
  for (int i = threadIdx.x; i < 2048; i += 256)
    sh[i] = (i < na) ? A[aStart + i] : B[bStart + (i - na)];
  __syncthreads();
  int k0 = threadIdx.x * 8;
  int lo = k0 - nb; if (lo < 0) lo = 0;
  int hi = k0 < na ? k0 : na;
  while (lo < hi){
    int mid = (lo + hi) >> 1;
    if (less4(sh[mid], sh[na + k0-1-mid])) lo = mid + 1; else hi = mid;
  }
  int i = lo, j = k0 - lo;
  #pragma unroll
  for (int e = 0; e < 8; ++e){
    bool takeA = (j >= nb) || (i < na && less4(sh[i], sh[na + j]));
    uint4 v = takeA ? sh[i] : sh[na + j];
    if (takeA) ++i; else ++j;
    O[k0 + e] = v;
  }
}

__global__ __launch_bounds__(256) void kmergef(const uint2* __restrict__ src,
                                               uint2* __restrict__ dst, int L){
  __shared__ uint2 sh[2048];
  __shared__ int sAB[2];
  int gid = blockIdx.x;
  int b = gid >> 5, c = gid & 31;
  const uint2* base = src + ((size_t)b << 16);
  uint2* obase = dst + ((size_t)b << 16);
  int co = c * 2048;
  int pair = co / (2*L);
  int ko = co - pair*2*L;
  const uint2* A = base + (size_t)pair*2*L;
  const uint2* B = A + L;
  uint2* O = obase + (size_t)pair*2*L + ko;
  if (threadIdx.x < 2){
    int k = ko + (int)threadIdx.x * 2048;
    int lo = k - L; if (lo < 0) lo = 0;
    int hi = k < L ? k : L;
    while (lo < hi){
      int mid = (lo + hi) >> 1;
      if (less2(A[mid], B[k-1-mid])) lo = mid + 1; else hi = mid;
    }
    sAB[threadIdx.x] = lo;
  }
  __syncthreads();
  int aStart = sAB[0];
  int na = sAB[1] - aStart;
  int nb = 2048 - na;
  int bStart = ko - aStart;
  for (int i = threadIdx.x; i < 2048; i += 256)
    sh[i] = (i < na) ? A[aStart + i] : B[bStart + (i - na)];
  __syncthreads();
  int k0 = threadIdx.x * 8;
  int lo = k0 - nb; if (lo < 0) lo = 0;
  int hi = k0 < na ? k0 : na;
  while (lo < hi){
    int mid = (lo + hi) >> 1;
    if (less2(sh[mid], sh[na + k0-1-mid])) lo = mid + 1; else hi = mid;
  }
  int i = lo, j = k0 - lo;
  #pragma unroll
  for (int e = 0; e < 8; ++e){
    bool takeA = (j >= nb) || (i < na && less2(sh[i], sh[na + j]));
    uint2 v = takeA ? sh[i] : sh[na + j];
    if (takeA) ++i; else ++j;
    O[k0 + e] = v;
  }
}

// Final face merge (L=32768): merge in LDS, decode ranks, write sorted_faces
// floats directly (3 dense streams) — replaces the old last round + ksfout.
__global__ __launch_bounds__(256) void kmergefOut(const uint2* __restrict__ src,
                                                  float* __restrict__ out){
  __shared__ __align__(16) float shf[6144];   // 24 KB; aliased as uint2[2048] below
  __shared__ int sAB[2];
  uint2* sh = (uint2*)shf;
  const int L = 32768;
  int gid = blockIdx.x;                       // 1024 = 32 batches x 32 chunks
  int b = gid >> 5, c = gid & 31;
  const uint2* A = src + ((size_t)b << 16);
  const uint2* B = A + L;
  int ko = c * 2048;
  if (threadIdx.x < 2){
    int k = ko + (int)threadIdx.x * 2048;
    int lo = k - L; if (lo < 0) lo = 0;
    int hi = k < L ? k : L;
    while (lo < hi){
      int mid = (lo + hi) >> 1;
      if (less2(A[mid], B[k-1-mid])) lo = mid + 1; else hi = mid;
    }
    sAB[threadIdx.x] = lo;
  }
  __syncthreads();
  int aStart = sAB[0];
  int na = sAB[1] - aStart;
  int nb = 2048 - na;
  int bStart = ko - aStart;
  for (int i = threadIdx.x; i < 2048; i += 256)
    sh[i] = (i < na) ? A[aStart + i] : B[bStart + (i - na)];
  __syncthreads();
  int k0 = threadIdx.x * 8;
  int lo = k0 - nb; if (lo < 0) lo = 0;
  int hi = k0 < na ? k0 : na;
  while (lo < hi){
    int mid = (lo + hi) >> 1;
    if (less2(sh[mid], sh[na + k0-1-mid])) lo = mid + 1; else hi = mid;
  }
  int i = lo, j = k0 - lo;
  uint2 v[8];
  #pragma unroll
  for (int e = 0; e < 8; ++e){
    bool takeA = (j >= nb) || (i < na && less2(sh[i], sh[na + j]));
    v[e] = takeA ? sh[i] : sh[na + j];
    if (takeA) ++i; else ++j;
  }
  __syncthreads();                            // all LDS src reads done
  #pragma unroll
  for (int e = 0; e < 8; ++e){
    int o = (k0 + e) * 3;
    shf[o+0] = (float)(v[e].x >> 15);         // r0
    shf[o+1] = (float)(v[e].y & 0x7FFFu);     // r1
    shf[o+2] = (float)(v[e].y >> 15);         // r2
  }
  __syncthreads();
  size_t basef = 75497600 + ((size_t)b*65536 + (size_t)ko)*3;
  for (int q = threadIdx.x; q < 6144; q += 256) out[basef + q] = shf[q];
}
// -----------------------------------------------------------------------------

// Fused inverse-permutation + per-vertex quantization table.
// Q[(b<<15)+pos] = packed (qx | qy<<8 | qz<<16) of sorted-position pos — the
// quantization is a pure function of the vertex, computed ONCE here (coalesced)
// instead of per face-vertex in kfacesB (6x redundancy + 16B gathers).
__global__ void kinvq(const uint4* __restrict__ S, int* __restrict__ inv,
                      unsigned* __restrict__ Q){
  #pragma clang fp contract(off)
  int id = blockIdx.x*256 + threadIdx.x;
  int b = id >> 15, j = id & (NV-1);
  uint4 s = S[id];
  inv[(b<<15) + (int)s.w] = j;
  float c[3]; c[0] = fdec(s.z); c[1] = fdec(s.y); c[2] = fdec(s.x); // (x,y,z)
  unsigned qw = 0;
  #pragma unroll
  for (int cc = 0; cc < 3; ++cc){
    float t = ((c[cc] + 1.0f) * 0.5f) * 128.0f - 0.5f;
    float rq = rintf(t);
    int qi = (int)rq;
    qi = qi < 0 ? 0 : (qi > 127 ? 127 : qi);
    qw |= ((unsigned)qi) << (8*cc);
  }
  Q[id] = qw;
}

// LDS-staged output: gather packed 4B quant codes per face-vertex (128KB/batch,
// L2-resident per XCD via swizzle), then emit all four regions with
// lane-contiguous (full-cacheline) stores.
__global__ __launch_bounds__(256) void kfacesB(const int* __restrict__ faces,
                                               const unsigned* __restrict__ Q,
                                               float* __restrict__ out){
  __shared__ __align__(16) float shq[2304];   // 256 faces x 9 quantized values
  __shared__ float shm[256];                  // attention value per face
  int p = blockIdx.x;
  int l = ((p & 7) << 10) | (p >> 3);         // 8192 = 8 x 1024, bijective
  int b = l >> 8, c = l & 255;
  int t = threadIdx.x;
  {
    size_t fb = ((size_t)(l*256 + t))*3;
    int f0 = faces[fb+0], f1 = faces[fb+1], f2 = faces[fb+2];
    bool mask = (f0 != -1) & (f1 != -1) & (f2 != -1);
    shm[t] = mask ? 1.0f : 0.0f;
    int fv[3] = {mask ? f0 : 0, mask ? f1 : 0, mask ? f2 : 0};
    #pragma unroll
    for (int k = 0; k < 3; ++k){
      unsigned qw = Q[(b<<15) + fv[k]];
      shq[t*9 + k*3 + 0] = (float)( qw        & 0xFFu);
      shq[t*9 + k*3 + 1] = (float)((qw >> 8 ) & 0xFFu);
      shq[t*9 + k*3 + 2] = (float)((qw >> 16) & 0xFFu);
    }
  }
  __syncthreads();
  // codes/dq: 16B-aligned block bases -> float4 stores (576 per block)
  float4* cp = (float4*)(out + 37748864 + (size_t)l*2304);
  float4* dp = (float4*)(out + 56623232 + (size_t)l*2304);
  for (int r = t; r < 576; r += 256){
    int e0 = r*4;
    float4 q = *(const float4*)&shq[e0];
    float m0 = shm[(unsigned)(e0  )/9u];
    float m1 = shm[(unsigned)(e0+1)/9u];
    float m2 = shm[(unsigned)(e0+2)/9u];
    float m3 = shm[(unsigned)(e0+3)/9u];
    float4 cv;
    cv.x = m0 != 0.0f ? q.x : -1.0f;
    cv.y = m1 != 0.0f ? q.y : -1.0f;
    cv.z = m2 != 0.0f ? q.z : -1.0f;
    cv.w = m3 != 0.0f ? q.w : -1.0f;
    cp[r] = cv;
    dp[r] = q;
  }
  // ids/attn: +1 float offset (misaligned) -> dense scalar dword stores
  size_t idsBase  = (size_t)b*589826 + 1 + (size_t)c*2304;
  size_t attnBase = 18874432 + idsBase;
  #pragma unroll
  for (int r = 0; r < 9; ++r){
    int idx = r*256 + t;
    float q = shq[idx];
    float m = shm[(unsigned)idx/9u];
    float cv = m != 0.0f ? q : -1.0f;
    out[idsBase + idx]  = cv;
    out[attnBase + idx] = m;
  }
  if (c == 0 && t == 0){
    out[(size_t)b*589826]                     = -1.0f;
    out[(size_t)b*589826 + 589825]            = -1.0f;
    out[18874432 + (size_t)b*589826]          = -1.0f;
    out[18874432 + (size_t)b*589826 + 589825] = -1.0f;
  }
}

extern "C" void kernel_launch(void* const* d_in, const int* in_sizes, int n_in,
                              void* d_out, int out_size, void* d_ws, size_t ws_size,
                              hipStream_t stream){
  const float* vert  = (const float*)d_in[0];
  const int*   faces = (const int*)d_in[1];
  float* out = (float*)d_out;

  uint4*    S           = (uint4*)d_ws;                         // 16 MiB
  uint4*    S2          = (uint4*)((char*)d_ws + 16777216);     // 16 MiB
  uint2*    FKa         = (uint2*)((char*)d_ws + 16777216);     // reuses S2
  unsigned* Q           = (unsigned*)((char*)d_ws + 16777216);  // aliases FKa (4 MiB)
  uint2*    FKb         = (uint2*)d_ws;                         // reuses S
  int*      inv         = (int*)((char*)d_ws + 33554432);       // 4 MiB
  float*    center      = (float*)((char*)d_ws + 37748736);     // 384 KiB
  unsigned* longestBits = (unsigned*)((char*)d_ws + 38141952);  // 4 B

  hipMemsetAsync(longestBits, 0, 4, stream);
  kminmax<<<PCOUNT/256, 256, 0, stream>>>(vert, center, longestBits);

  // vertex sort: fused keygen + local 2048-tiles, then 4 merge rounds (ends in S)
  klocalv<<<BATCH*(NV/VT), 256, 0, stream>>>(vert, center, longestBits, S);
  kmergev<<<BATCH*16, 256, 0, stream>>>(S,  S2, 2048);
  kmergev<<<BATCH*16, 256, 0, stream>>>(S2, S,  4096);
  kmergev<<<BATCH*16, 256, 0, stream>>>(S,  S2, 8192);
  kmergev<<<BATCH*16, 256, 0, stream>>>(S2, S,  16384);

  kinvq<<<(BATCH*NV)/256, 256, 0, stream>>>(S, inv, Q);         // S2 dead -> Q live
  kfacesB<<<(BATCH*NF)/256, 256, 0, stream>>>(faces, Q, out);   // Q dead after

  // face sort: fused FK keygen + local 4096-tiles, 3 merge rounds, final+output
  klocalf<<<BATCH*(NF/FT), 256, 0, stream>>>(faces, inv, FKa);  // overwrites Q
  kmergef<<<BATCH*32, 256, 0, stream>>>(FKa, FKb, 4096);
  kmergef<<<BATCH*32, 256, 0, stream>>>(FKb, FKa, 8192);
  kmergef<<<BATCH*32, 256, 0, stream>>>(FKa, FKb, 16384);
  kmergefOut<<<BATCH*32, 256, 0, stream>>>(FKb, out);
}

// Round 4
// 674.755 us; speedup vs baseline: 1.5047x; 1.1485x over previous
//
#include <hip/hip_runtime.h>
#include <stdint.h>

#define BATCH 32
#define NV 32768
#define NF 65536
#define PCOUNT (NV*3)

// Output layout (floats, concatenated in reference return order):
// input_ids      (32, 589826)      @ 0
// attention_mask (32, 589826)      @ 18874432
// codes          (32, 65536, 3, 3) @ 37748864
// dq             (32, 65536, 3, 3) @ 56623232
// sorted_faces   (32, 65536, 3)    @ 75497600
//
// Workspace: S @0 (16MB) | S2/FKa/Q @16MB (16MB) | inv @32MB (4MB) | center | lbits
// FKb reuses S region. Q aliases FKa (stream-ordered, disjoint live ranges).

__device__ __forceinline__ unsigned fenc(float f){
  unsigned u = __float_as_uint(f);
  return (u & 0x80000000u) ? ~u : (u | 0x80000000u);
}
__device__ __forceinline__ float fdec(unsigned e){
  unsigned u = (e & 0x80000000u) ? (e & 0x7FFFFFFFu) : ~e;
  return __uint_as_float(u);
}

__global__ void kminmax(const float* __restrict__ vert, float* __restrict__ center,
                        unsigned* __restrict__ longestBits){
  int p = blockIdx.x*256 + threadIdx.x;   // 0..98303
  float mn = 3.4e38f, mx = -3.4e38f;
  #pragma unroll
  for (int b = 0; b < BATCH; ++b) {
    float v = vert[(size_t)b*PCOUNT + p];
    mn = fminf(mn, v); mx = fmaxf(mx, v);
  }
  center[p] = __fadd_rn(mn, mx) * 0.5f;
  float r = __fsub_rn(mx, mn);
  for (int off = 32; off > 0; off >>= 1) r = fmaxf(r, __shfl_down(r, off, 64));
  if ((threadIdx.x & 63) == 0) atomicMax(longestBits, __float_as_uint(r));
}

__device__ __forceinline__ bool less4(uint4 a, uint4 b){
  if (a.x != b.x) return a.x < b.x;
  if (a.y != b.y) return a.y < b.y;
  if (a.z != b.z) return a.z < b.z;
  return a.w < b.w;                        // idx: unique -> total order
}
// Face record: lo=(r0<<15)|f, hi=(r2<<15)|r1 -> compare hi then lo == (r2,r1,r0,f).
__device__ __forceinline__ bool less2(uint2 a, uint2 b){
  if (a.y != b.y) return a.y < b.y;
  return a.x < b.x;                        // f: unique -> total order
}

// ---------------- Register-blocksort local sorts -----------------------------
// Per-thread in-register bitonic run sort + LDS merge-path rounds (2 barriers
// per round instead of bitonic's 66-78 barriered, bank-conflicted stages).
// XOR swizzle keeps linear passes and writebacks at the LDS conflict floor.
#define VT 2048   // vertex tile (8/thread)
#define FT 4096   // face tile (16/thread)
#define SWV(i) ((i) ^ (((i) >> 3) & 7))     // uint4: spread bank-quads
#define SWF(i) ((i) ^ (((i) >> 4) & 15))    // uint2: spread bank-pairs

// Fused kvkeys + blocksort: build {fenc(z),fenc(y),fenc(x),idx}, sort tile, write S.
__global__ __launch_bounds__(256) void klocalv(const float* __restrict__ vert,
                                               const float* __restrict__ center,
                                               const unsigned* __restrict__ longestBits,
                                               uint4* __restrict__ S){
  __shared__ uint4 sh[VT];
  int blockBase = blockIdx.x * VT;        // tiles never cross batch boundary
  float L = __uint_as_float(*longestBits);
  float rl = __fdiv_rn(1.0f, L);
  for (int i = threadIdx.x; i < VT; i += 256){
    int id = blockBase + i;
    int vi = id & (NV-1);
    size_t vb = (size_t)(id >> 15)*PCOUNT + (size_t)vi*3;
    float nx = __fsub_rn(vert[vb+0], center[vi*3+0]);
    float ny = __fsub_rn(vert[vb+1], center[vi*3+1]);
    float nz = __fsub_rn(vert[vb+2], center[vi*3+2]);
    float x = __fmul_rn(nx, rl);
    float y = __fmul_rn(ny, rl);
    float z = __fmul_rn(nz, rl);
    uint4 s; s.x = fenc(z); s.y = fenc(y); s.z = fenc(x); s.w = (unsigned)vi;
    sh[SWV(i)] = s;
  }
  __syncthreads();
  int t = threadIdx.x;
  int k0 = t * 8;
  uint4 v[8];
  #pragma unroll
  for (int e = 0; e < 8; ++e) v[e] = sh[SWV(k0 + e)];
  // in-register bitonic sort of 8 (all indices compile-time)
  #pragma unroll
  for (int k = 2; k <= 8; k <<= 1){
    #pragma unroll
    for (int j = k >> 1; j > 0; j >>= 1){
      #pragma unroll
      for (int i = 0; i < 8; ++i){
        int l = i ^ j;
        if (l > i){
          bool up = ((i & k) == 0);
          bool sw = up ? less4(v[l], v[i]) : less4(v[i], v[l]);
          if (sw){ uint4 tmp = v[i]; v[i] = v[l]; v[l] = tmp; }
        }
      }
    }
  }
  #pragma unroll
  for (int e = 0; e < 8; ++e) sh[SWV(k0 + e)] = v[e];
  __syncthreads();
  // LDS merge-path rounds: run width w -> 2w
  for (int w = 8; w < VT; w <<= 1){
    int base = k0 & ~(2*w - 1);
    int ko = k0 - base;
    int lo = ko - w; if (lo < 0) lo = 0;
    int hi = ko < w ? ko : w;
    while (lo < hi){
      int mid = (lo + hi) >> 1;
      if (less4(sh[SWV(base + mid)], sh[SWV(base + w + ko-1-mid)])) lo = mid + 1; else hi = mid;
    }
    int i = lo, j = ko - lo;
    uint4 m[8];
    #pragma unroll
    for (int e = 0; e < 8; ++e){
      bool takeA = (j >= w) || (i < w && less4(sh[SWV(base + i)], sh[SWV(base + w + j)]));
      m[e] = takeA ? sh[SWV(base + i)] : sh[SWV(base + w + j)];
      if (takeA) ++i; else ++j;
    }
    __syncthreads();
    #pragma unroll
    for (int e = 0; e < 8; ++e) sh[SWV(k0 + e)] = m[e];
    __syncthreads();
  }
  uint4* basep = S + (size_t)blockBase;
  for (int i = threadIdx.x; i < VT; i += 256) basep[i] = sh[SWV(i)];
}

// Fused kfacesFK + blocksort: build face records, sort tile, write F.
__global__ __launch_bounds__(256) void klocalf(const int* __restrict__ faces,
                                               const int* __restrict__ inv,
                                               uint2* __restrict__ F){
  __shared__ uint2 sh[FT];
  int blockBase = blockIdx.x * FT;        // tiles never cross batch boundary
  int b = blockBase >> 16;
  const int* invb = inv + (b << 15);
  for (int i = threadIdx.x; i < FT; i += 256){
    int id = blockBase + i;
    int f = id & (NF-1);
    size_t fb = (size_t)id*3;
    int f0 = faces[fb+0], f1 = faces[fb+1], f2 = faces[fb+2];
    unsigned r0 = (unsigned)invb[f0 & (NV-1)];
    unsigned r1 = (unsigned)invb[f1 & (NV-1)];
    unsigned r2 = (unsigned)invb[f2 & (NV-1)];
    uint2 r; r.x = (r0 << 15) | (unsigned)f; r.y = (r2 << 15) | r1;
    sh[SWF(i)] = r;
  }
  __syncthreads();
  int t = threadIdx.x;
  int k0 = t * 16;
  uint2 v[16];
  #pragma unroll
  for (int e = 0; e < 16; ++e) v[e] = sh[SWF(k0 + e)];
  // in-register bitonic sort of 16
  #pragma unroll
  for (int k = 2; k <= 16; k <<= 1){
    #pragma unroll
    for (int j = k >> 1; j > 0; j >>= 1){
      #pragma unroll
      for (int i = 0; i < 16; ++i){
        int l = i ^ j;
        if (l > i){
          bool up = ((i & k) == 0);
          bool sw = up ? less2(v[l], v[i]) : less2(v[i], v[l]);
          if (sw){ uint2 tmp = v[i]; v[i] = v[l]; v[l] = tmp; }
        }
      }
    }
  }
  #pragma unroll
  for (int e = 0; e < 16; ++e) sh[SWF(k0 + e)] = v[e];
  __syncthreads();
  for (int w = 16; w < FT; w <<= 1){
    int base = k0 & ~(2*w - 1);
    int ko = k0 - base;
    int lo = ko - w; if (lo < 0) lo = 0;
    int hi = ko < w ? ko : w;
    while (lo < hi){
      int mid = (lo + hi) >> 1;
      if (less2(sh[SWF(base + mid)], sh[SWF(base + w + ko-1-mid)])) lo = mid + 1; else hi = mid;
    }
    int i = lo, j = ko - lo;
    uint2 m[16];
    #pragma unroll
    for (int e = 0; e < 16; ++e){
      bool takeA = (j >= w) || (i < w && less2(sh[SWF(base + i)], sh[SWF(base + w + j)]));
      m[e] = takeA ? sh[SWF(base + i)] : sh[SWF(base + w + j)];
      if (takeA) ++i; else ++j;
    }
    __syncthreads();
    #pragma unroll
    for (int e = 0; e < 16; ++e) sh[SWF(k0 + e)] = m[e];
    __syncthreads();
  }
  uint2* basep = F + (size_t)blockBase;
  for (int i = threadIdx.x; i < FT; i += 256) basep[i] = sh[SWF(i)];
}

// ---------------- LDS-staged merge-path merge rounds --------------------------
__global__ __launch_bounds__(256) void kmergev(const uint4* __restrict__ src,
                                               uint4* __restrict__ dst, int L){
  __shared__ uint4 sh[2048];
  __shared__ int sAB[2];
  int gid = blockIdx.x;
  int b = gid >> 4, c = gid & 15;
  const uint4* base = src + ((size_t)b << 15);
  uint4* obase = dst + ((size_t)b << 15);
  int co = c * 2048;
  int pair = co / (2*L);
  int ko = co - pair*2*L;
  const uint4* A = base + (size_t)pair*2*L;
  const uint4* B = A + L;
  uint4* O = obase + (size_t)pair*2*L + ko;
  if (threadIdx.x < 2){
    int k = ko + (int)threadIdx.x * 2048;
    int lo = k - L; if (lo < 0) lo = 0;
    int hi = k < L ? k : L;
    while (lo < hi){
      int mid = (lo + hi) >> 1;
      if (less4(A[mid], B[k-1-mid])) lo = mid + 1; else hi = mid;
    }
    sAB[threadIdx.x] = lo;
  }
  __syncthreads();
  int aStart = sAB[0];
  int na = sAB[1] - aStart;
  int nb = 2048 - na;
  int bStart = ko - aStart;
  for (int i = threadIdx.x; i < 2048; i += 256)
    sh[i] = (i < na) ? A[aStart + i] : B[bStart + (i - na)];
  __syncthreads();
  int k0 = threadIdx.x * 8;
  int lo = k0 - nb; if (lo < 0) lo = 0;
  int hi = k0 < na ? k0 : na;
  while (lo < hi){
    int mid = (lo + hi) >> 1;
    if (less4(sh[mid], sh[na + k0-1-mid])) lo = mid + 1; else hi = mid;
  }
  int i = lo, j = k0 - lo;
  #pragma unroll
  for (int e = 0; e < 8; ++e){
    bool takeA = (j >= nb) || (i < na && less4(sh[i], sh[na + j]));
    uint4 v = takeA ? sh[i] : sh[na + j];
    if (takeA) ++i; else ++j;
    O[k0 + e] = v;
  }
}

__global__ __launch_bounds__(256) void kmergef(const uint2* __restrict__ src,
                                               uint2* __restrict__ dst, int L){
  __shared__ uint2 sh[2048];
  __shared__ int sAB[2];
  int gid = blockIdx.x;
  int b = gid >> 5, c = gid & 31;
  const uint2* base = src + ((size_t)b << 16);
  uint2* obase = dst + ((size_t)b << 16);
  int co = c * 2048;
  int pair = co / (2*L);
  int ko = co - pair*2*L;
  const uint2* A = base + (size_t)pair*2*L;
  const uint2* B = A + L;
  uint2* O = obase + (size_t)pair*2*L + ko;
  if (threadIdx.x < 2){
    int k = ko + (int)threadIdx.x * 2048;
    int lo = k - L; if (lo < 0) lo = 0;
    int hi = k < L ? k : L;
    while (lo < hi){
      int mid = (lo + hi) >> 1;
      if (less2(A[mid], B[k-1-mid])) lo = mid + 1; else hi = mid;
    }
    sAB[threadIdx.x] = lo;
  }
  __syncthreads();
  int aStart = sAB[0];
  int na = sAB[1] - aStart;
  int nb = 2048 - na;
  int bStart = ko - aStart;
  for (int i = threadIdx.x; i < 2048; i += 256)
    sh[i] = (i < na) ? A[aStart + i] : B[bStart + (i - na)];
  __syncthreads();
  int k0 = threadIdx.x * 8;
  int lo = k0 - nb; if (lo < 0) lo = 0;
  int hi = k0 < na ? k0 : na;
  while (lo < hi){
    int mid = (lo + hi) >> 1;
    if (less2(sh[mid], sh[na + k0-1-mid])) lo = mid + 1; else hi = mid;
  }
  int i = lo, j = k0 - lo;
  #pragma unroll
  for (int e = 0; e < 8; ++e){
    bool takeA = (j >= nb) || (i < na && less2(sh[i], sh[na + j]));
    uint2 v = takeA ? sh[i] : sh[na + j];
    if (takeA) ++i; else ++j;
    O[k0 + e] = v;
  }
}

// Final face merge (L=32768): merge in LDS, decode ranks, write sorted_faces
// floats directly (3 dense streams).
__global__ __launch_bounds__(256) void kmergefOut(const uint2* __restrict__ src,
                                                  float* __restrict__ out){
  __shared__ __align__(16) float shf[6144];   // 24 KB; aliased as uint2[2048] below
  __shared__ int sAB[2];
  uint2* sh = (uint2*)shf;
  const int L = 32768;
  int gid = blockIdx.x;                       // 1024 = 32 batches x 32 chunks
  int b = gid >> 5, c = gid & 31;
  const uint2* A = src + ((size_t)b << 16);
  const uint2* B = A + L;
  int ko = c * 2048;
  if (threadIdx.x < 2){
    int k = ko + (int)threadIdx.x * 2048;
    int lo = k - L; if (lo < 0) lo = 0;
    int hi = k < L ? k : L;
    while (lo < hi){
      int mid = (lo + hi) >> 1;
      if (less2(A[mid], B[k-1-mid])) lo = mid + 1; else hi = mid;
    }
    sAB[threadIdx.x] = lo;
  }
  __syncthreads();
  int aStart = sAB[0];
  int na = sAB[1] - aStart;
  int nb = 2048 - na;
  int bStart = ko - aStart;
  for (int i = threadIdx.x; i < 2048; i += 256)
    sh[i] = (i < na) ? A[aStart + i] : B[bStart + (i - na)];
  __syncthreads();
  int k0 = threadIdx.x * 8;
  int lo = k0 - nb; if (lo < 0) lo = 0;
  int hi = k0 < na ? k0 : na;
  while (lo < hi){
    int mid = (lo + hi) >> 1;
    if (less2(sh[mid], sh[na + k0-1-mid])) lo = mid + 1; else hi = mid;
  }
  int i = lo, j = k0 - lo;
  uint2 v[8];
  #pragma unroll
  for (int e = 0; e < 8; ++e){
    bool takeA = (j >= nb) || (i < na && less2(sh[i], sh[na + j]));
    v[e] = takeA ? sh[i] : sh[na + j];
    if (takeA) ++i; else ++j;
  }
  __syncthreads();                            // all LDS src reads done
  #pragma unroll
  for (int e = 0; e < 8; ++e){
    int o = (k0 + e) * 3;
    shf[o+0] = (float)(v[e].x >> 15);         // r0
    shf[o+1] = (float)(v[e].y & 0x7FFFu);     // r1
    shf[o+2] = (float)(v[e].y >> 15);         // r2
  }
  __syncthreads();
  size_t basef = 75497600 + ((size_t)b*65536 + (size_t)ko)*3;
  for (int q = threadIdx.x; q < 6144; q += 256) out[basef + q] = shf[q];
}
// -----------------------------------------------------------------------------

// Fused inverse-permutation + per-vertex packed quantization table.
__global__ void kinvq(const uint4* __restrict__ S, int* __restrict__ inv,
                      unsigned* __restrict__ Q){
  #pragma clang fp contract(off)
  int id = blockIdx.x*256 + threadIdx.x;
  int b = id >> 15, j = id & (NV-1);
  uint4 s = S[id];
  inv[(b<<15) + (int)s.w] = j;
  float c[3]; c[0] = fdec(s.z); c[1] = fdec(s.y); c[2] = fdec(s.x); // (x,y,z)
  unsigned qw = 0;
  #pragma unroll
  for (int cc = 0; cc < 3; ++cc){
    float t = ((c[cc] + 1.0f) * 0.5f) * 128.0f - 0.5f;
    float rq = rintf(t);
    int qi = (int)rq;
    qi = qi < 0 ? 0 : (qi > 127 ? 127 : qi);
    qw |= ((unsigned)qi) << (8*cc);
  }
  Q[id] = qw;
}

// LDS-staged output: gather packed 4B quant codes per face-vertex (128KB/batch,
// L2-resident per XCD via swizzle), emit all four regions lane-contiguous.
__global__ __launch_bounds__(256) void kfacesB(const int* __restrict__ faces,
                                               const unsigned* __restrict__ Q,
                                               float* __restrict__ out){
  __shared__ __align__(16) float shq[2304];   // 256 faces x 9 quantized values
  __shared__ float shm[256];                  // attention value per face
  int p = blockIdx.x;
  int l = ((p & 7) << 10) | (p >> 3);         // 8192 = 8 x 1024, bijective
  int b = l >> 8, c = l & 255;
  int t = threadIdx.x;
  {
    size_t fb = ((size_t)(l*256 + t))*3;
    int f0 = faces[fb+0], f1 = faces[fb+1], f2 = faces[fb+2];
    bool mask = (f0 != -1) & (f1 != -1) & (f2 != -1);
    shm[t] = mask ? 1.0f : 0.0f;
    int fv[3] = {mask ? f0 : 0, mask ? f1 : 0, mask ? f2 : 0};
    #pragma unroll
    for (int k = 0; k < 3; ++k){
      unsigned qw = Q[(b<<15) + fv[k]];
      shq[t*9 + k*3 + 0] = (float)( qw        & 0xFFu);
      shq[t*9 + k*3 + 1] = (float)((qw >> 8 ) & 0xFFu);
      shq[t*9 + k*3 + 2] = (float)((qw >> 16) & 0xFFu);
    }
  }
  __syncthreads();
  // codes/dq: 16B-aligned block bases -> float4 stores (576 per block)
  float4* cp = (float4*)(out + 37748864 + (size_t)l*2304);
  float4* dp = (float4*)(out + 56623232 + (size_t)l*2304);
  for (int r = t; r < 576; r += 256){
    int e0 = r*4;
    float4 q = *(const float4*)&shq[e0];
    float m0 = shm[(unsigned)(e0  )/9u];
    float m1 = shm[(unsigned)(e0+1)/9u];
    float m2 = shm[(unsigned)(e0+2)/9u];
    float m3 = shm[(unsigned)(e0+3)/9u];
    float4 cv;
    cv.x = m0 != 0.0f ? q.x : -1.0f;
    cv.y = m1 != 0.0f ? q.y : -1.0f;
    cv.z = m2 != 0.0f ? q.z : -1.0f;
    cv.w = m3 != 0.0f ? q.w : -1.0f;
    cp[r] = cv;
    dp[r] = q;
  }
  // ids/attn: +1 float offset (misaligned) -> dense scalar dword stores
  size_t idsBase  = (size_t)b*589826 + 1 + (size_t)c*2304;
  size_t attnBase = 18874432 + idsBase;
  #pragma unroll
  for (int r = 0; r < 9; ++r){
    int idx = r*256 + t;
    float q = shq[idx];
    float m = shm[(unsigned)idx/9u];
    float cv = m != 0.0f ? q : -1.0f;
    out[idsBase + idx]  = cv;
    out[attnBase + idx] = m;
  }
  if (c == 0 && t == 0){
    out[(size_t)b*589826]                     = -1.0f;
    out[(size_t)b*589826 + 589825]            = -1.0f;
    out[18874432 + (size_t)b*589826]          = -1.0f;
    out[18874432 + (size_t)b*589826 + 589825] = -1.0f;
  }
}

extern "C" void kernel_launch(void* const* d_in, const int* in_sizes, int n_in,
                              void* d_out, int out_size, void* d_ws, size_t ws_size,
                              hipStream_t stream){
  const float* vert  = (const float*)d_in[0];
  const int*   faces = (const int*)d_in[1];
  float* out = (float*)d_out;

  uint4*    S           = (uint4*)d_ws;                         // 16 MiB
  uint4*    S2          = (uint4*)((char*)d_ws + 16777216);     // 16 MiB
  uint2*    FKa         = (uint2*)((char*)d_ws + 16777216);     // reuses S2
  unsigned* Q           = (unsigned*)((char*)d_ws + 16777216);  // aliases FKa (4 MiB)
  uint2*    FKb         = (uint2*)d_ws;                         // reuses S
  int*      inv         = (int*)((char*)d_ws + 33554432);       // 4 MiB
  float*    center      = (float*)((char*)d_ws + 37748736);     // 384 KiB
  unsigned* longestBits = (unsigned*)((char*)d_ws + 38141952);  // 4 B

  hipMemsetAsync(longestBits, 0, 4, stream);
  kminmax<<<PCOUNT/256, 256, 0, stream>>>(vert, center, longestBits);

  // vertex sort: fused keygen + blocksort 2048-tiles, then 4 merge rounds (ends in S)
  klocalv<<<BATCH*(NV/VT), 256, 0, stream>>>(vert, center, longestBits, S);
  kmergev<<<BATCH*16, 256, 0, stream>>>(S,  S2, 2048);
  kmergev<<<BATCH*16, 256, 0, stream>>>(S2, S,  4096);
  kmergev<<<BATCH*16, 256, 0, stream>>>(S,  S2, 8192);
  kmergev<<<BATCH*16, 256, 0, stream>>>(S2, S,  16384);

  kinvq<<<(BATCH*NV)/256, 256, 0, stream>>>(S, inv, Q);         // S2 dead -> Q live
  kfacesB<<<(BATCH*NF)/256, 256, 0, stream>>>(faces, Q, out);   // Q dead after

  // face sort: fused FK keygen + blocksort 4096-tiles, 3 merge rounds, final+output
  klocalf<<<BATCH*(NF/FT), 256, 0, stream>>>(faces, inv, FKa);  // overwrites Q
  kmergef<<<BATCH*32, 256, 0, stream>>>(FKa, FKb, 4096);
  kmergef<<<BATCH*32, 256, 0, stream>>>(FKb, FKa, 8192);
  kmergef<<<BATCH*32, 256, 0, stream>>>(FKa, FKb, 16384);
  kmergefOut<<<BATCH*32, 256, 0, stream>>>(FKb, out);
}

// Round 5
// 643.124 us; speedup vs baseline: 1.5787x; 1.0492x over previous
//
#include <hip/hip_runtime.h>
#include <stdint.h>

#define BATCH 32
#define NV 32768
#define NF 65536
#define PCOUNT (NV*3)

// Output layout (floats, concatenated in reference return order):
// input_ids      (32, 589826)      @ 0
// attention_mask (32, 589826)      @ 18874432
// codes          (32, 65536, 3, 3) @ 37748864
// dq             (32, 65536, 3, 3) @ 56623232
// sorted_faces   (32, 65536, 3)    @ 75497600
//
// Workspace: S/FKb @0 (16MB) | S2/Q/FKa @16MB (16MB) | inv @32MB (4MB) | center | lbits
// All aliases are stream-ordered with disjoint live ranges:
//   S dead after kmergevQ (reads S, writes Q+inv; never re-materializes sorted S).
//   Q dead after kfacesB; FKa (same region) written by klocalf afterwards.

__device__ __forceinline__ unsigned fenc(float f){
  unsigned u = __float_as_uint(f);
  return (u & 0x80000000u) ? ~u : (u | 0x80000000u);
}
__device__ __forceinline__ float fdec(unsigned e){
  unsigned u = (e & 0x80000000u) ? (e & 0x7FFFFFFFu) : ~e;
  return __uint_as_float(u);
}

__global__ void kminmax(const float* __restrict__ vert, float* __restrict__ center,
                        unsigned* __restrict__ longestBits){
  int p = blockIdx.x*256 + threadIdx.x;   // 0..98303
  float mn = 3.4e38f, mx = -3.4e38f;
  #pragma unroll
  for (int b = 0; b < BATCH; ++b) {
    float v = vert[(size_t)b*PCOUNT + p];
    mn = fminf(mn, v); mx = fmaxf(mx, v);
  }
  center[p] = __fadd_rn(mn, mx) * 0.5f;
  float r = __fsub_rn(mx, mn);
  for (int off = 32; off > 0; off >>= 1) r = fmaxf(r, __shfl_down(r, off, 64));
  if ((threadIdx.x & 63) == 0) atomicMax(longestBits, __float_as_uint(r));
}

__device__ __forceinline__ bool less4(uint4 a, uint4 b){
  if (a.x != b.x) return a.x < b.x;
  if (a.y != b.y) return a.y < b.y;
  if (a.z != b.z) return a.z < b.z;
  return a.w < b.w;                        // idx: unique -> total order
}
// Face record: lo=(r0<<15)|f, hi=(r2<<15)|r1 -> compare hi then lo == (r2,r1,r0,f).
__device__ __forceinline__ bool less2(uint2 a, uint2 b){
  if (a.y != b.y) return a.y < b.y;
  return a.x < b.x;                        // f: unique -> total order
}

// ---------------- Register-blocksort local sorts -----------------------------
// Per-thread in-register bitonic run sort + LDS merge-path rounds.
// 64KB LDS tiles (512 threads, 2 blocks/CU): one extra cheap LDS round each
// replaces one full global merge round (33.6MB r+w + a launch).
#define VT 4096   // vertex tile (512 thr x 8/thread)
#define FT 8192   // face tile  (512 thr x 16/thread)
#define SWV(i) ((i) ^ (((i) >> 3) & 7))     // uint4: spread bank-quads
#define SWF(i) ((i) ^ (((i) >> 4) & 15))    // uint2: spread bank-pairs

// Fused kvkeys + blocksort: build {fenc(z),fenc(y),fenc(x),idx}, sort tile, write S.
__global__ __launch_bounds__(512) void klocalv(const float* __restrict__ vert,
                                               const float* __restrict__ center,
                                               const unsigned* __restrict__ longestBits,
                                               uint4* __restrict__ S){
  __shared__ uint4 sh[VT];                  // 64 KB
  int blockBase = blockIdx.x * VT;          // tiles never cross batch boundary
  float L = __uint_as_float(*longestBits);
  float rl = __fdiv_rn(1.0f, L);
  for (int i = threadIdx.x; i < VT; i += 512){
    int id = blockBase + i;
    int vi = id & (NV-1);
    size_t vb = (size_t)(id >> 15)*PCOUNT + (size_t)vi*3;
    float nx = __fsub_rn(vert[vb+0], center[vi*3+0]);
    float ny = __fsub_rn(vert[vb+1], center[vi*3+1]);
    float nz = __fsub_rn(vert[vb+2], center[vi*3+2]);
    float x = __fmul_rn(nx, rl);
    float y = __fmul_rn(ny, rl);
    float z = __fmul_rn(nz, rl);
    uint4 s; s.x = fenc(z); s.y = fenc(y); s.z = fenc(x); s.w = (unsigned)vi;
    sh[SWV(i)] = s;
  }
  __syncthreads();
  int t = threadIdx.x;
  int k0 = t * 8;
  uint4 v[8];
  #pragma unroll
  for (int e = 0; e < 8; ++e) v[e] = sh[SWV(k0 + e)];
  // in-register bitonic sort of 8 (all indices compile-time)
  #pragma unroll
  for (int k = 2; k <= 8; k <<= 1){
    #pragma unroll
    for (int j = k >> 1; j > 0; j >>= 1){
      #pragma unroll
      for (int i = 0; i < 8; ++i){
        int l = i ^ j;
        if (l > i){
          bool up = ((i & k) == 0);
          bool sw = up ? less4(v[l], v[i]) : less4(v[i], v[l]);
          if (sw){ uint4 tmp = v[i]; v[i] = v[l]; v[l] = tmp; }
        }
      }
    }
  }
  #pragma unroll
  for (int e = 0; e < 8; ++e) sh[SWV(k0 + e)] = v[e];
  __syncthreads();
  // LDS merge-path rounds: run width w -> 2w
  for (int w = 8; w < VT; w <<= 1){
    int base = k0 & ~(2*w - 1);
    int ko = k0 - base;
    int lo = ko - w; if (lo < 0) lo = 0;
    int hi = ko < w ? ko : w;
    while (lo < hi){
      int mid = (lo + hi) >> 1;
      if (less4(sh[SWV(base + mid)], sh[SWV(base + w + ko-1-mid)])) lo = mid + 1; else hi = mid;
    }
    int i = lo, j = ko - lo;
    uint4 m[8];
    #pragma unroll
    for (int e = 0; e < 8; ++e){
      bool takeA = (j >= w) || (i < w && less4(sh[SWV(base + i)], sh[SWV(base + w + j)]));
      m[e] = takeA ? sh[SWV(base + i)] : sh[SWV(base + w + j)];
      if (takeA) ++i; else ++j;
    }
    __syncthreads();
    #pragma unroll
    for (int e = 0; e < 8; ++e) sh[SWV(k0 + e)] = m[e];
    __syncthreads();
  }
  uint4* basep = S + (size_t)blockBase;
  for (int i = threadIdx.x; i < VT; i += 512) basep[i] = sh[SWV(i)];
}

// Fused kfacesFK + blocksort: build face records, sort tile, write F.
__global__ __launch_bounds__(512) void klocalf(const int* __restrict__ faces,
                                               const int* __restrict__ inv,
                                               uint2* __restrict__ F){
  __shared__ uint2 sh[FT];                  // 64 KB
  int blockBase = blockIdx.x * FT;          // tiles never cross batch boundary
  int b = blockBase >> 16;
  const int* invb = inv + (b << 15);
  for (int i = threadIdx.x; i < FT; i += 512){
    int id = blockBase + i;
    int f = id & (NF-1);
    size_t fb = (size_t)id*3;
    int f0 = faces[fb+0], f1 = faces[fb+1], f2 = faces[fb+2];
    unsigned r0 = (unsigned)invb[f0 & (NV-1)];
    unsigned r1 = (unsigned)invb[f1 & (NV-1)];
    unsigned r2 = (unsigned)invb[f2 & (NV-1)];
    uint2 r; r.x = (r0 << 15) | (unsigned)f; r.y = (r2 << 15) | r1;
    sh[SWF(i)] = r;
  }
  __syncthreads();
  int t = threadIdx.x;
  int k0 = t * 16;
  uint2 v[16];
  #pragma unroll
  for (int e = 0; e < 16; ++e) v[e] = sh[SWF(k0 + e)];
  // in-register bitonic sort of 16
  #pragma unroll
  for (int k = 2; k <= 16; k <<= 1){
    #pragma unroll
    for (int j = k >> 1; j > 0; j >>= 1){
      #pragma unroll
      for (int i = 0; i < 16; ++i){
        int l = i ^ j;
        if (l > i){
          bool up = ((i & k) == 0);
          bool sw = up ? less2(v[l], v[i]) : less2(v[i], v[l]);
          if (sw){ uint2 tmp = v[i]; v[i] = v[l]; v[l] = tmp; }
        }
      }
    }
  }
  #pragma unroll
  for (int e = 0; e < 16; ++e) sh[SWF(k0 + e)] = v[e];
  __syncthreads();
  for (int w = 16; w < FT; w <<= 1){
    int base = k0 & ~(2*w - 1);
    int ko = k0 - base;
    int lo = ko - w; if (lo < 0) lo = 0;
    int hi = ko < w ? ko : w;
    while (lo < hi){
      int mid = (lo + hi) >> 1;
      if (less2(sh[SWF(base + mid)], sh[SWF(base + w + ko-1-mid)])) lo = mid + 1; else hi = mid;
    }
    int i = lo, j = ko - lo;
    uint2 m[16];
    #pragma unroll
    for (int e = 0; e < 16; ++e){
      bool takeA = (j >= w) || (i < w && less2(sh[SWF(base + i)], sh[SWF(base + w + j)]));
      m[e] = takeA ? sh[SWF(base + i)] : sh[SWF(base + w + j)];
      if (takeA) ++i; else ++j;
    }
    __syncthreads();
    #pragma unroll
    for (int e = 0; e < 16; ++e) sh[SWF(k0 + e)] = m[e];
    __syncthreads();
  }
  uint2* basep = F + (size_t)blockBase;
  for (int i = threadIdx.x; i < FT; i += 512) basep[i] = sh[SWF(i)];
}

// ---------------- LDS-staged merge-path merge rounds --------------------------
__global__ __launch_bounds__(256) void kmergev(const uint4* __restrict__ src,
                                               uint4* __restrict__ dst, int L){
  __shared__ uint4 sh[2048];
  __shared__ int sAB[2];
  int gid = blockIdx.x;
  int b = gid >> 4, c = gid & 15;
  const uint4* base = src + ((size_t)b << 15);
  uint4* obase = dst + ((size_t)b << 15);
  int co = c * 2048;
  int pair = co / (2*L);
  int ko = co - pair*2*L;
  const uint4* A = base + (size_t)pair*2*L;
  const uint4* B = A + L;
  uint4* O = obase + (size_t)pair*2*L + ko;
  if (threadIdx.x < 2){
    int k = ko + (int)threadIdx.x * 2048;
    int lo = k - L; if (lo < 0) lo = 0;
    int hi = k < L ? k : L;
    while (lo < hi){
      int mid = (lo + hi) >> 1;
      if (less4(A[mid], B[k-1-mid])) lo = mid + 1; else hi = mid;
    }
    sAB[threadIdx.x] = lo;
  }
  __syncthreads();
  int aStart = sAB[0];
  int na = sAB[1] - aStart;
  int nb = 2048 - na;
  int bStart = ko - aStart;
  for (int i = threadIdx.x; i < 2048; i += 256)
    sh[i] = (i < na) ? A[aStart + i] : B[bStart + (i - na)];
  __syncthreads();
  int k0 = threadIdx.x * 8;
  int lo = k0 - nb; if (lo < 0) lo = 0;
  int hi = k0 < na ? k0 : na;
  while (lo < hi){
    int mid = (lo + hi) >> 1;
    if (less4(sh[mid], sh[na + k0-1-mid])) lo = mid + 1; else hi = mid;
  }
  int i = lo, j = k0 - lo;
  #pragma unroll
  for (int e = 0; e < 8; ++e){
    bool takeA = (j >= nb) || (i < na && less4(sh[i], sh[na + j]));
    uint4 v = takeA ? sh[i] : sh[na + j];
    if (takeA) ++i; else ++j;
    O[k0 + e] = v;
  }
}

// Final vertex merge (L=16384) fused with inverse-permutation + packed quant
// table: the merged record never round-trips through global sorted S.
__global__ __launch_bounds__(256) void kmergevQ(const uint4* __restrict__ src,
                                                int* __restrict__ inv,
                                                unsigned* __restrict__ Q){
  #pragma clang fp contract(off)
  __shared__ uint4 sh[2048];
  __shared__ int sAB[2];
  const int L = 16384;
  int gid = blockIdx.x;
  int b = gid >> 4, c = gid & 15;
  const uint4* A = src + ((size_t)b << 15);
  const uint4* B = A + L;
  int ko = c * 2048;                          // pair==0 (2L == NV)
  if (threadIdx.x < 2){
    int k = ko + (int)threadIdx.x * 2048;
    int lo = k - L; if (lo < 0) lo = 0;
    int hi = k < L ? k : L;
    while (lo < hi){
      int mid = (lo + hi) >> 1;
      if (less4(A[mid], B[k-1-mid])) lo = mid + 1; else hi = mid;
    }
    sAB[threadIdx.x] = lo;
  }
  __syncthreads();
  int aStart = sAB[0];
  int na = sAB[1] - aStart;
  int nb = 2048 - na;
  int bStart = ko - aStart;
  for (int i = threadIdx.x; i < 2048; i += 256)
    sh[i] = (i < na) ? A[aStart + i] : B[bStart + (i - na)];
  __syncthreads();
  int k0 = threadIdx.x * 8;
  int lo = k0 - nb; if (lo < 0) lo = 0;
  int hi = k0 < na ? k0 : na;
  while (lo < hi){
    int mid = (lo + hi) >> 1;
    if (less4(sh[mid], sh[na + k0-1-mid])) lo = mid + 1; else hi = mid;
  }
  int i = lo, j = k0 - lo;
  #pragma unroll
  for (int e = 0; e < 8; ++e){
    bool takeA = (j >= nb) || (i < na && less4(sh[i], sh[na + j]));
    uint4 s = takeA ? sh[i] : sh[na + j];
    if (takeA) ++i; else ++j;
    int pos = ko + k0 + e;                    // final sorted index within batch
    inv[(b<<15) + (int)s.w] = pos;
    float cco[3]; cco[0] = fdec(s.z); cco[1] = fdec(s.y); cco[2] = fdec(s.x); // (x,y,z)
    unsigned qw = 0;
    #pragma unroll
    for (int cc = 0; cc < 3; ++cc){
      float tt = ((cco[cc] + 1.0f) * 0.5f) * 128.0f - 0.5f;
      float rq = rintf(tt);
      int qi = (int)rq;
      qi = qi < 0 ? 0 : (qi > 127 ? 127 : qi);
      qw |= ((unsigned)qi) << (8*cc);
    }
    Q[(b<<15) + pos] = qw;
  }
}

__global__ __launch_bounds__(256) void kmergef(const uint2* __restrict__ src,
                                               uint2* __restrict__ dst, int L){
  __shared__ uint2 sh[2048];
  __shared__ int sAB[2];
  int gid = blockIdx.x;
  int b = gid >> 5, c = gid & 31;
  const uint2* base = src + ((size_t)b << 16);
  uint2* obase = dst + ((size_t)b << 16);
  int co = c * 2048;
  int pair = co / (2*L);
  int ko = co - pair*2*L;
  const uint2* A = base + (size_t)pair*2*L;
  const uint2* B = A + L;
  uint2* O = obase + (size_t)pair*2*L + ko;
  if (threadIdx.x < 2){
    int k = ko + (int)threadIdx.x * 2048;
    int lo = k - L; if (lo < 0) lo = 0;
    int hi = k < L ? k : L;
    while (lo < hi){
      int mid = (lo + hi) >> 1;
      if (less2(A[mid], B[k-1-mid])) lo = mid + 1; else hi = mid;
    }
    sAB[threadIdx.x] = lo;
  }
  __syncthreads();
  int aStart = sAB[0];
  int na = sAB[1] - aStart;
  int nb = 2048 - na;
  int bStart = ko - aStart;
  for (int i = threadIdx.x; i < 2048; i += 256)
    sh[i] = (i < na) ? A[aStart + i] : B[bStart + (i - na)];
  __syncthreads();
  int k0 = threadIdx.x * 8;
  int lo = k0 - nb; if (lo < 0) lo = 0;
  int hi = k0 < na ? k0 : na;
  while (lo < hi){
    int mid = (lo + hi) >> 1;
    if (less2(sh[mid], sh[na + k0-1-mid])) lo = mid + 1; else hi = mid;
  }
  int i = lo, j = k0 - lo;
  #pragma unroll
  for (int e = 0; e < 8; ++e){
    bool takeA = (j >= nb) || (i < na && less2(sh[i], sh[na + j]));
    uint2 v = takeA ? sh[i] : sh[na + j];
    if (takeA) ++i; else ++j;
    O[k0 + e] = v;
  }
}

// Final face merge (L=32768): merge in LDS, decode ranks, write sorted_faces
// floats directly (3 dense streams).
__global__ __launch_bounds__(256) void kmergefOut(const uint2* __restrict__ src,
                                                  float* __restrict__ out){
  __shared__ __align__(16) float shf[6144];   // 24 KB; aliased as uint2[2048] below
  __shared__ int sAB[2];
  uint2* sh = (uint2*)shf;
  const int L = 32768;
  int gid = blockIdx.x;                       // 1024 = 32 batches x 32 chunks
  int b = gid >> 5, c = gid & 31;
  const uint2* A = src + ((size_t)b << 16);
  const uint2* B = A + L;
  int ko = c * 2048;
  if (threadIdx.x < 2){
    int k = ko + (int)threadIdx.x * 2048;
    int lo = k - L; if (lo < 0) lo = 0;
    int hi = k < L ? k : L;
    while (lo < hi){
      int mid = (lo + hi) >> 1;
      if (less2(A[mid], B[k-1-mid])) lo = mid + 1; else hi = mid;
    }
    sAB[threadIdx.x] = lo;
  }
  __syncthreads();
  int aStart = sAB[0];
  int na = sAB[1] - aStart;
  int nb = 2048 - na;
  int bStart = ko - aStart;
  for (int i = threadIdx.x; i < 2048; i += 256)
    sh[i] = (i < na) ? A[aStart + i] : B[bStart + (i - na)];
  __syncthreads();
  int k0 = threadIdx.x * 8;
  int lo = k0 - nb; if (lo < 0) lo = 0;
  int hi = k0 < na ? k0 : na;
  while (lo < hi){
    int mid = (lo + hi) >> 1;
    if (less2(sh[mid], sh[na + k0-1-mid])) lo = mid + 1; else hi = mid;
  }
  int i = lo, j = k0 - lo;
  uint2 v[8];
  #pragma unroll
  for (int e = 0; e < 8; ++e){
    bool takeA = (j >= nb) || (i < na && less2(sh[i], sh[na + j]));
    v[e] = takeA ? sh[i] : sh[na + j];
    if (takeA) ++i; else ++j;
  }
  __syncthreads();                            // all LDS src reads done
  #pragma unroll
  for (int e = 0; e < 8; ++e){
    int o = (k0 + e) * 3;
    shf[o+0] = (float)(v[e].x >> 15);         // r0
    shf[o+1] = (float)(v[e].y & 0x7FFFu);     // r1
    shf[o+2] = (float)(v[e].y >> 15);         // r2
  }
  __syncthreads();
  size_t basef = 75497600 + ((size_t)b*65536 + (size_t)ko)*3;
  for (int q = threadIdx.x; q < 6144; q += 256) out[basef + q] = shf[q];
}
// -----------------------------------------------------------------------------

// LDS-staged output: gather packed 4B quant codes per face-vertex (128KB/batch,
// L2-resident per XCD via swizzle), emit all four regions lane-contiguous.
__global__ __launch_bounds__(256) void kfacesB(const int* __restrict__ faces,
                                               const unsigned* __restrict__ Q,
                                               float* __restrict__ out){
  __shared__ __align__(16) float shq[2304];   // 256 faces x 9 quantized values
  __shared__ float shm[256];                  // attention value per face
  int p = blockIdx.x;
  int l = ((p & 7) << 10) | (p >> 3);         // 8192 = 8 x 1024, bijective
  int b = l >> 8, c = l & 255;
  int t = threadIdx.x;
  {
    size_t fb = ((size_t)(l*256 + t))*3;
    int f0 = faces[fb+0], f1 = faces[fb+1], f2 = faces[fb+2];
    bool mask = (f0 != -1) & (f1 != -1) & (f2 != -1);
    shm[t] = mask ? 1.0f : 0.0f;
    int fv[3] = {mask ? f0 : 0, mask ? f1 : 0, mask ? f2 : 0};
    #pragma unroll
    for (int k = 0; k < 3; ++k){
      unsigned qw = Q[(b<<15) + fv[k]];
      shq[t*9 + k*3 + 0] = (float)( qw        & 0xFFu);
      shq[t*9 + k*3 + 1] = (float)((qw >> 8 ) & 0xFFu);
      shq[t*9 + k*3 + 2] = (float)((qw >> 16) & 0xFFu);
    }
  }
  __syncthreads();
  // codes/dq: 16B-aligned block bases -> float4 stores (576 per block)
  float4* cp = (float4*)(out + 37748864 + (size_t)l*2304);
  float4* dp = (float4*)(out + 56623232 + (size_t)l*2304);
  for (int r = t; r < 576; r += 256){
    int e0 = r*4;
    float4 q = *(const float4*)&shq[e0];
    float m0 = shm[(unsigned)(e0  )/9u];
    float m1 = shm[(unsigned)(e0+1)/9u];
    float m2 = shm[(unsigned)(e0+2)/9u];
    float m3 = shm[(unsigned)(e0+3)/9u];
    float4 cv;
    cv.x = m0 != 0.0f ? q.x : -1.0f;
    cv.y = m1 != 0.0f ? q.y : -1.0f;
    cv.z = m2 != 0.0f ? q.z : -1.0f;
    cv.w = m3 != 0.0f ? q.w : -1.0f;
    cp[r] = cv;
    dp[r] = q;
  }
  // ids/attn: +1 float offset (misaligned) -> dense scalar dword stores
  size_t idsBase  = (size_t)b*589826 + 1 + (size_t)c*2304;
  size_t attnBase = 18874432 + idsBase;
  #pragma unroll
  for (int r = 0; r < 9; ++r){
    int idx = r*256 + t;
    float q = shq[idx];
    float m = shm[(unsigned)idx/9u];
    float cv = m != 0.0f ? q : -1.0f;
    out[idsBase + idx]  = cv;
    out[attnBase + idx] = m;
  }
  if (c == 0 && t == 0){
    out[(size_t)b*589826]                     = -1.0f;
    out[(size_t)b*589826 + 589825]            = -1.0f;
    out[18874432 + (size_t)b*589826]          = -1.0f;
    out[18874432 + (size_t)b*589826 + 589825] = -1.0f;
  }
}

extern "C" void kernel_launch(void* const* d_in, const int* in_sizes, int n_in,
                              void* d_out, int out_size, void* d_ws, size_t ws_size,
                              hipStream_t stream){
  const float* vert  = (const float*)d_in[0];
  const int*   faces = (const int*)d_in[1];
  float* out = (float*)d_out;

  uint4*    S           = (uint4*)d_ws;                         // 16 MiB
  uint4*    S2          = (uint4*)((char*)d_ws + 16777216);     // 16 MiB
  uint2*    FKa         = (uint2*)((char*)d_ws + 16777216);     // reuses S2
  unsigned* Q           = (unsigned*)((char*)d_ws + 16777216);  // aliases FKa (4 MiB)
  uint2*    FKb         = (uint2*)d_ws;                         // reuses S
  int*      inv         = (int*)((char*)d_ws + 33554432);       // 4 MiB
  float*    center      = (float*)((char*)d_ws + 37748736);     // 384 KiB
  unsigned* longestBits = (unsigned*)((char*)d_ws + 38141952);  // 4 B

  hipMemsetAsync(longestBits, 0, 4, stream);
  kminmax<<<PCOUNT/256, 256, 0, stream>>>(vert, center, longestBits);

  // vertex sort: fused keygen + blocksort 4096-tiles, 2 merge rounds,
  // final round fused with inv+Q emission (sorted S never re-materialized)
  klocalv<<<BATCH*(NV/VT), 512, 0, stream>>>(vert, center, longestBits, S);
  kmergev<<<BATCH*16, 256, 0, stream>>>(S,  S2, 4096);
  kmergev<<<BATCH*16, 256, 0, stream>>>(S2, S,  8192);
  kmergevQ<<<BATCH*16, 256, 0, stream>>>(S, inv, Q);            // S dead after

  kfacesB<<<(BATCH*NF)/256, 256, 0, stream>>>(faces, Q, out);   // Q dead after

  // face sort: fused FK keygen + blocksort 8192-tiles, 2 merge rounds, final+output
  klocalf<<<BATCH*(NF/FT), 512, 0, stream>>>(faces, inv, FKa);  // overwrites Q
  kmergef<<<BATCH*32, 256, 0, stream>>>(FKa, FKb, 8192);
  kmergef<<<BATCH*32, 256, 0, stream>>>(FKb, FKa, 16384);
  kmergefOut<<<BATCH*32, 256, 0, stream>>>(FKa, out);
}